// Round 2
// baseline (1699.780 us; speedup 1.0000x reference)
//
#include <hip/hip_runtime.h>
#include <cstdint>
#include <cstddef>

typedef unsigned short u16;
typedef __attribute__((ext_vector_type(8))) __bf16 bf16x8;
typedef __attribute__((ext_vector_type(4))) float f32x4;

__device__ __forceinline__ f32x4 mfma_16x16x32(bf16x8 a, bf16x8 b, f32x4 c) {
  return __builtin_amdgcn_mfma_f32_16x16x32_bf16(a, b, c, 0, 0, 0);
}

__device__ __forceinline__ u16 f2bf(float f) {
  union { float f; uint32_t u; } c; c.f = f;
  uint32_t u = c.u + 0x7FFFu + ((c.u >> 16) & 1u);
  return (u16)(u >> 16);
}

__device__ __forceinline__ float bf2f(u16 x) {
  union { uint32_t u; float f; } c; c.u = ((uint32_t)x) << 16;
  return c.f;
}

__device__ __forceinline__ void gload_lds16(const void* g, void* l) {
  __builtin_amdgcn_global_load_lds(
      (__attribute__((address_space(1))) void*)(uintptr_t)g,
      (__attribute__((address_space(3))) void*)l, 16, 0, 0);
}

// ---------------------------------------------------------------------------
// GEMM: C[M,N] = A[M,K] @ Bt[N,K]^T + bias (+C if ACC), optional ReLU.
// A, Bt bf16 row-major (K contiguous, strides lda/ldb). 128x128 tile, BK=32.
// ---------------------------------------------------------------------------
template<bool OUT_BF16, bool RELU, bool ACC>
__global__ __launch_bounds__(256, 2) void gemm_bt(
    const u16* __restrict__ A, int lda, const u16* __restrict__ Bt, int ldb,
    const float* __restrict__ bias, void* Cout, int ldc,
    int M, int N, int K)
{
  __shared__ u16 ldsA[128 * 32];
  __shared__ u16 ldsB[128 * 32];

  const int tid = threadIdx.x;
  const int lane = tid & 63, wave = tid >> 6;
  const int wr = wave >> 1, wc = wave & 1;
  const int m0 = blockIdx.x * 128, n0 = blockIdx.y * 128;

  const int c0 = tid, c1 = tid + 256;
  const int ar0 = c0 >> 2, ak0 = (c0 & 3) * 8;
  const int ar1 = c1 >> 2, ak1 = (c1 & 3) * 8;

  const bool av0 = (m0 + ar0) < M;
  const bool av1 = (m0 + ar1) < M;
  const u16* Ag0 = A + (size_t)(m0 + ar0) * lda + ak0;
  const u16* Ag1 = A + (size_t)(m0 + ar1) * lda + ak1;
  const u16* Bg0 = Bt + (size_t)(n0 + ar0) * ldb + ak0;
  const u16* Bg1 = Bt + (size_t)(n0 + ar1) * ldb + ak1;

  f32x4 acc[4][4] = {};

  const int fr = lane & 15, fo = (lane >> 4) * 8;

  for (int k0 = 0; k0 < K; k0 += 32) {
    if (av0) gload_lds16(Ag0 + k0, &ldsA[c0 * 8]);
    if (av1) gload_lds16(Ag1 + k0, &ldsA[c1 * 8]);
    gload_lds16(Bg0 + k0, &ldsB[c0 * 8]);
    gload_lds16(Bg1 + k0, &ldsB[c1 * 8]);
    asm volatile("s_waitcnt vmcnt(0)" ::: "memory");
    __syncthreads();

    bf16x8 af[4], bfr[4];
    #pragma unroll
    for (int m = 0; m < 4; m++)
      af[m] = *(const bf16x8*)&ldsA[(wr * 64 + m * 16 + fr) * 32 + fo];
    #pragma unroll
    for (int n = 0; n < 4; n++)
      bfr[n] = *(const bf16x8*)&ldsB[(wc * 64 + n * 16 + fr) * 32 + fo];
    #pragma unroll
    for (int m = 0; m < 4; m++) {
      #pragma unroll
      for (int n = 0; n < 4; n++)
        acc[m][n] = mfma_16x16x32(af[m], bfr[n], acc[m][n]);
    }
    __syncthreads();
  }

  const int g = lane >> 4;
  #pragma unroll
  for (int m = 0; m < 4; m++) {
    #pragma unroll
    for (int n = 0; n < 4; n++) {
      const int gcol = n0 + wc * 64 + n * 16 + fr;
      const float bv = bias ? bias[gcol] : 0.f;
      #pragma unroll
      for (int r = 0; r < 4; r++) {
        const int grow = m0 + wr * 64 + m * 16 + g * 4 + r;
        if (grow < M) {
          float v = acc[m][n][r] + bv;
          if (ACC) v += bf2f(((const u16*)Cout)[(size_t)grow * ldc + gcol]);
          if (RELU) v = fmaxf(v, 0.f);
          if (OUT_BF16) ((u16*)Cout)[(size_t)grow * ldc + gcol] = f2bf(v);
          else         ((float*)Cout)[(size_t)grow * ldc + gcol] = v;
        }
      }
    }
  }
}

// ---------------------------------------------------------------------------
// Weight transpose+convert: src f32 [K][N] -> dst bf16 [N][K]
// ---------------------------------------------------------------------------
__global__ void wconv_t(const float* __restrict__ src, u16* __restrict__ dst,
                        int K, int N)
{
  __shared__ float tile[32][33];
  const int n0 = blockIdx.x * 32, k0 = blockIdx.y * 32;
  const int tx = threadIdx.x, ty = threadIdx.y;
  #pragma unroll
  for (int i = 0; i < 4; i++)
    tile[ty + i * 8][tx] = src[(size_t)(k0 + ty + i * 8) * N + n0 + tx];
  __syncthreads();
  #pragma unroll
  for (int i = 0; i < 4; i++)
    dst[(size_t)(n0 + ty + i * 8) * K + k0 + tx] = f2bf(tile[tx][ty + i * 8]);
}

// ---------------------------------------------------------------------------
// Positional encoding add (video): vf32 = video + pe, vbf = bf16(vf32)
// ---------------------------------------------------------------------------
__global__ __launch_bounds__(256) void pe_video_k(const float* __restrict__ video,
                                                  float* __restrict__ vf32,
                                                  u16* __restrict__ vbf)
{
  const int r = blockIdx.x;
  const int s = r & 2047;
  const int d0 = threadIdx.x * 4;
  const size_t base = (size_t)r * 1024 + d0;
  float4 v = *(const float4*)&video[base];
  const float coef = -9.210340371976184f / 1024.f;
  float o[4];
  float in[4] = {v.x, v.y, v.z, v.w};
  #pragma unroll
  for (int i = 0; i < 4; i++) {
    int d = d0 + i;
    int j = d >> 1;
    float dv = expf((float)(2 * j) * coef);
    float arg = (float)s * dv;
    float pe = (d & 1) ? cosf(arg) : sinf(arg);
    o[i] = in[i] + pe;
  }
  *(float4*)&vf32[base] = make_float4(o[0], o[1], o[2], o[3]);
  uint2 pk;
  pk.x = (uint32_t)f2bf(o[0]) | ((uint32_t)f2bf(o[1]) << 16);
  pk.y = (uint32_t)f2bf(o[2]) | ((uint32_t)f2bf(o[3]) << 16);
  *(uint2*)&vbf[base] = pk;
}

__global__ __launch_bounds__(128) void pe_text_k(const float* __restrict__ text,
                                                 u16* __restrict__ tbf)
{
  const int r = blockIdx.x;
  const int s = r % 100;
  const int d0 = threadIdx.x * 4;
  const size_t base = (size_t)r * 512 + d0;
  float4 v = *(const float4*)&text[base];
  const float coef = -9.210340371976184f / 512.f;
  float o[4];
  float in[4] = {v.x, v.y, v.z, v.w};
  #pragma unroll
  for (int i = 0; i < 4; i++) {
    int d = d0 + i;
    int j = d >> 1;
    float dv = expf((float)(2 * j) * coef);
    float arg = (float)s * dv;
    float pe = (d & 1) ? cosf(arg) : sinf(arg);
    o[i] = in[i] + pe;
  }
  uint2 pk;
  pk.x = (uint32_t)f2bf(o[0]) | ((uint32_t)f2bf(o[1]) << 16);
  pk.y = (uint32_t)f2bf(o[2]) | ((uint32_t)f2bf(o[3]) << 16);
  *(uint2*)&tbf[base] = pk;
}

// ---------------------------------------------------------------------------
// LayerNorm with residual: x = LN(x + delta)*g+b ; delta is bf16
// ---------------------------------------------------------------------------
__global__ __launch_bounds__(256) void ln_res(float* __restrict__ x,
                                              const u16* __restrict__ delta,
                                              const float* __restrict__ gamma,
                                              const float* __restrict__ beta,
                                              u16* __restrict__ xbf)
{
  const int row = blockIdx.x;
  const size_t base = (size_t)row * 1024;
  const int t = threadIdx.x;
  const int d0 = t * 4;
  float4 xv = *(const float4*)&x[base + d0];
  uint2 dv2 = *(const uint2*)&delta[base + d0];
  float v0 = xv.x + bf2f((u16)(dv2.x & 0xFFFF));
  float v1 = xv.y + bf2f((u16)(dv2.x >> 16));
  float v2 = xv.z + bf2f((u16)(dv2.y & 0xFFFF));
  float v3 = xv.w + bf2f((u16)(dv2.y >> 16));
  float s = v0 + v1 + v2 + v3;
  float q = v0 * v0 + v1 * v1 + v2 * v2 + v3 * v3;
  #pragma unroll
  for (int d = 32; d >= 1; d >>= 1) { s += __shfl_xor(s, d); q += __shfl_xor(q, d); }
  __shared__ float red[8];
  const int lane = t & 63, w = t >> 6;
  if (lane == 0) { red[w] = s; red[4 + w] = q; }
  __syncthreads();
  float S = red[0] + red[1] + red[2] + red[3];
  float Qs = red[4] + red[5] + red[6] + red[7];
  const float mu = S * (1.f / 1024.f);
  const float var = Qs * (1.f / 1024.f) - mu * mu;
  const float rs = rsqrtf(var + 1e-5f);
  float4 gv = *(const float4*)&gamma[d0];
  float4 bv = *(const float4*)&beta[d0];
  float o0 = (v0 - mu) * rs * gv.x + bv.x;
  float o1 = (v1 - mu) * rs * gv.y + bv.y;
  float o2 = (v2 - mu) * rs * gv.z + bv.z;
  float o3 = (v3 - mu) * rs * gv.w + bv.w;
  *(float4*)&x[base + d0] = make_float4(o0, o1, o2, o3);
  uint2 pk;
  pk.x = (uint32_t)f2bf(o0) | ((uint32_t)f2bf(o1) << 16);
  pk.y = (uint32_t)f2bf(o2) | ((uint32_t)f2bf(o3) << 16);
  *(uint2*)&xbf[base + d0] = pk;
}

// ---------------------------------------------------------------------------
// Cross attention: per block = 64 q-rows x one (b,h).
// ---------------------------------------------------------------------------
#define A_ST 100
#define A_STP 128
#define A_DK 64
#define A_DM 1024
#define A_SQ 2048

__global__ __launch_bounds__(256) void attn_kernel(
    const u16* __restrict__ Q, const u16* __restrict__ Kb,
    const u16* __restrict__ Vb, const int* __restrict__ mask,
    u16* __restrict__ Out)
{
  __shared__ u16 ldsK[A_STP * A_DK];     // [j][k]
  __shared__ u16 ldsVt[A_DK * A_STP];    // [d][j]
  __shared__ u16 ldsP[64 * A_STP];       // [q][j]
  __shared__ float smadd[A_STP];

  const int tid = threadIdx.x, lane = tid & 63, w = tid >> 6;
  const int qb = blockIdx.x, bh = blockIdx.y;
  const int b = bh >> 4, h = bh & 15;

  for (int c = tid; c < A_STP * A_DK / 8; c += 256) {
    int j = c >> 3, kc = (c & 7) * 8;
    uint4 val = make_uint4(0u, 0u, 0u, 0u);
    if (j < A_ST) val = *(const uint4*)&Kb[((size_t)(b * A_ST + j)) * A_DM + h * A_DK + kc];
    *(uint4*)&ldsK[j * A_DK + kc] = val;
  }
  for (int idx = tid; idx < A_DK * A_STP; idx += 256) {
    int d = idx >> 7, j = idx & 127;
    u16 v = 0;
    if (j < A_ST) v = Vb[((size_t)(b * A_ST + j)) * A_DM + h * A_DK + d];
    ldsVt[d * A_STP + j] = v;
  }
  for (int j = tid; j < A_STP; j += 256)
    smadd[j] = (j < A_ST && mask[b * A_ST + j] != 0) ? 0.f : -1e30f;
  for (int idx = tid; idx < 64 * A_STP; idx += 256) ldsP[idx] = 0;

  const int fr = lane & 15, g = lane >> 4, fo = g * 8;

  const size_t qrow = (size_t)(b * A_SQ + qb * 64 + w * 16 + fr) * A_DM + h * A_DK;
  bf16x8 qf0 = *(const bf16x8*)&Q[qrow + fo];
  bf16x8 qf1 = *(const bf16x8*)&Q[qrow + 32 + fo];

  __syncthreads();

  float sc[7][4];
  #pragma unroll
  for (int t = 0; t < 7; t++) {
    f32x4 a = {};
    bf16x8 kf0 = *(const bf16x8*)&ldsK[(t * 16 + fr) * A_DK + fo];
    bf16x8 kf1 = *(const bf16x8*)&ldsK[(t * 16 + fr) * A_DK + 32 + fo];
    a = mfma_16x16x32(qf0, kf0, a);
    a = mfma_16x16x32(qf1, kf1, a);
    #pragma unroll
    for (int r = 0; r < 4; r++)
      sc[t][r] = a[r] * 0.125f + smadd[t * 16 + fr];
  }

  #pragma unroll
  for (int r = 0; r < 4; r++) {
    float m = sc[0][r];
    #pragma unroll
    for (int t = 1; t < 7; t++) m = fmaxf(m, sc[t][r]);
    #pragma unroll
    for (int d = 8; d >= 1; d >>= 1) m = fmaxf(m, __shfl_xor(m, d));
    float ssum = 0.f;
    #pragma unroll
    for (int t = 0; t < 7; t++) { float p = __expf(sc[t][r] - m); sc[t][r] = p; ssum += p; }
    #pragma unroll
    for (int d = 8; d >= 1; d >>= 1) ssum += __shfl_xor(ssum, d);
    float is = 1.f / ssum;
    #pragma unroll
    for (int t = 0; t < 7; t++)
      ldsP[(w * 16 + g * 4 + r) * A_STP + t * 16 + fr] = f2bf(sc[t][r] * is);
  }
  __syncthreads();

  bf16x8 pa[4];
  #pragma unroll
  for (int kk = 0; kk < 4; kk++)
    pa[kk] = *(const bf16x8*)&ldsP[(w * 16 + fr) * A_STP + kk * 32 + fo];
  #pragma unroll
  for (int nt = 0; nt < 4; nt++) {
    f32x4 a = {};
    #pragma unroll
    for (int kk = 0; kk < 4; kk++) {
      bf16x8 vf = *(const bf16x8*)&ldsVt[(nt * 16 + fr) * A_STP + kk * 32 + fo];
      a = mfma_16x16x32(pa[kk], vf, a);
    }
    #pragma unroll
    for (int r = 0; r < 4; r++) {
      size_t orow = (size_t)(b * A_SQ + qb * 64 + w * 16 + g * 4 + r) * A_DM + h * A_DK + nt * 16 + fr;
      Out[orow] = f2bf(a[r]);
    }
  }
}

// ---------------------------------------------------------------------------
extern "C" void kernel_launch(void* const* d_in, const int* in_sizes, int n_in,
                              void* d_out, int out_size, void* d_ws, size_t ws_size,
                              hipStream_t stream) {
  const float* video = (const float*)d_in[0];
  const float* text  = (const float*)d_in[1];
  const int*   text_mask = (const int*)d_in[2];
  const float* Wq_w = (const float*)d_in[3];
  const float* Wq_b = (const float*)d_in[4];
  const float* Wk_w = (const float*)d_in[5];
  const float* Wk_b = (const float*)d_in[6];
  const float* Wv_w = (const float*)d_in[7];
  const float* Wv_b = (const float*)d_in[8];
  const float* Wo_w = (const float*)d_in[9];
  const float* Wo_b = (const float*)d_in[10];
  const float* fc1_w = (const float*)d_in[11];
  const float* fc1_b = (const float*)d_in[12];
  const float* fc2_w = (const float*)d_in[13];
  const float* fc2_b = (const float*)d_in[14];
  const float* n2_g = (const float*)d_in[15];
  const float* n2_b = (const float*)d_in[16];
  const float* n3_g = (const float*)d_in[17];
  const float* n3_b = (const float*)d_in[18];

  char* ws = (char*)d_ws;
  size_t off = 0;
  auto alloc = [&](size_t bytes) {
    char* p = ws + off;
    off += (bytes + 255) & ~(size_t)255;
    return p;
  };
  // persistent across layers
  u16* vbf = (u16*)alloc((size_t)8192 * 1024 * 2);     // 16 MB
  u16* tbf = (u16*)alloc((size_t)400 * 512 * 2);       // 0.4 MB
  // per-layer weight slots (rewritten each layer)
  u16* wqT = (u16*)alloc((size_t)1024 * 1024 * 2);     // 2 MB
  u16* wkT = (u16*)alloc((size_t)1024 * 512 * 2);      // 1 MB
  u16* wvT = (u16*)alloc((size_t)1024 * 512 * 2);      // 1 MB
  u16* woT = (u16*)alloc((size_t)1024 * 1024 * 2);     // 2 MB
  u16* f1T = (u16*)alloc((size_t)4096 * 1024 * 2);     // 8 MB
  u16* f2T = (u16*)alloc((size_t)1024 * 4096 * 2);     // 8 MB
  // union scratch S: {qbf,kbf,vvbf,abf} aliased by h1c (FF hidden chunk)
  char* S = alloc((size_t)35192832);                   // 33.6 MB
  u16* qbf  = (u16*)S;                                 // 16 MB
  u16* kbf  = (u16*)(S + 16777216);                    // 0.78 MB
  u16* vvbf = (u16*)(S + 16777216 + 819200);           // 0.78 MB
  u16* abf  = (u16*)(S + 16777216 + 1638400);          // 16 MB
  u16* h1c  = (u16*)S;                                 // 32 MB (8192x2048 bf16)
  // bf16 residual delta
  u16* dbf = (u16*)alloc((size_t)8192 * 1024 * 2);     // 16 MB
  // total ~93 MB

  float* vf32 = (float*)d_out;

  pe_video_k<<<8192, 256, 0, stream>>>(video, vf32, vbf);
  pe_text_k<<<400, 128, 0, stream>>>(text, tbf);

  dim3 tb(32, 8, 1);
  for (int l = 0; l < 4; ++l) {
    wconv_t<<<dim3(32, 32), tb, 0, stream>>>(Wq_w + (size_t)l * 1024 * 1024, wqT, 1024, 1024);
    wconv_t<<<dim3(32, 16), tb, 0, stream>>>(Wk_w + (size_t)l * 512 * 1024, wkT, 512, 1024);
    wconv_t<<<dim3(32, 16), tb, 0, stream>>>(Wv_w + (size_t)l * 512 * 1024, wvT, 512, 1024);
    wconv_t<<<dim3(32, 32), tb, 0, stream>>>(Wo_w + (size_t)l * 1024 * 1024, woT, 1024, 1024);
    wconv_t<<<dim3(128, 32), tb, 0, stream>>>(fc1_w + (size_t)l * 1024 * 4096, f1T, 1024, 4096);
    wconv_t<<<dim3(32, 128), tb, 0, stream>>>(fc2_w + (size_t)l * 4096 * 1024, f2T, 4096, 1024);

    gemm_bt<true, false, false><<<dim3(64, 8), 256, 0, stream>>>(
        vbf, 1024, wqT, 1024, Wq_b + l * 1024, qbf, 1024, 8192, 1024, 1024);
    gemm_bt<true, false, false><<<dim3(4, 8), 256, 0, stream>>>(
        tbf, 512, wkT, 512, Wk_b + l * 1024, kbf, 1024, 400, 1024, 512);
    gemm_bt<true, false, false><<<dim3(4, 8), 256, 0, stream>>>(
        tbf, 512, wvT, 512, Wv_b + l * 1024, vvbf, 1024, 400, 1024, 512);
    attn_kernel<<<dim3(32, 64), 256, 0, stream>>>(qbf, kbf, vvbf, text_mask, abf);
    gemm_bt<true, false, false><<<dim3(64, 8), 256, 0, stream>>>(
        abf, 1024, woT, 1024, Wo_b + l * 1024, dbf, 1024, 8192, 1024, 1024);
    ln_res<<<8192, 256, 0, stream>>>(vf32, dbf, n2_g + l * 1024, n2_b + l * 1024, vbf);

    // FF in two 2048-wide chunks: h1c = relu(vbf@f1 chunk), dbf (+)= h1c@f2 chunk
    for (int c = 0; c < 2; ++c) {
      gemm_bt<true, true, false><<<dim3(64, 16), 256, 0, stream>>>(
          vbf, 1024, f1T + (size_t)c * 2048 * 1024, 1024,
          fc1_b + l * 4096 + c * 2048, h1c, 2048, 8192, 2048, 1024);
      if (c == 0)
        gemm_bt<true, false, false><<<dim3(64, 8), 256, 0, stream>>>(
            h1c, 2048, f2T + (size_t)c * 2048, 4096,
            fc2_b + l * 1024, dbf, 1024, 8192, 1024, 2048);
      else
        gemm_bt<true, false, true><<<dim3(64, 8), 256, 0, stream>>>(
            h1c, 2048, f2T + (size_t)c * 2048, 4096,
            nullptr, dbf, 1024, 8192, 1024, 2048);
    }
    ln_res<<<8192, 256, 0, stream>>>(vf32, dbf, n3_g + l * 1024, n3_b + l * 1024, vbf);
  }
}

// Round 3
// 1548.017 us; speedup vs baseline: 1.0980x; 1.0980x over previous
//
#include <hip/hip_runtime.h>
#include <cstdint>
#include <cstddef>

typedef unsigned short u16;
typedef __attribute__((ext_vector_type(8))) __bf16 bf16x8;
typedef __attribute__((ext_vector_type(4))) float f32x4;

__device__ __forceinline__ f32x4 mfma_16x16x32(bf16x8 a, bf16x8 b, f32x4 c) {
  return __builtin_amdgcn_mfma_f32_16x16x32_bf16(a, b, c, 0, 0, 0);
}

__device__ __forceinline__ u16 f2bf(float f) {
  union { float f; uint32_t u; } c; c.f = f;
  uint32_t u = c.u + 0x7FFFu + ((c.u >> 16) & 1u);
  return (u16)(u >> 16);
}

__device__ __forceinline__ float bf2f(u16 x) {
  union { uint32_t u; float f; } c; c.u = ((uint32_t)x) << 16;
  return c.f;
}

__device__ __forceinline__ void gload_lds16(const void* g, void* l) {
  __builtin_amdgcn_global_load_lds(
      (__attribute__((address_space(1))) void*)(uintptr_t)g,
      (__attribute__((address_space(3))) void*)l, 16, 0, 0);
}

// ===========================================================================
// Deep-pipelined ring GEMM.  C[M,N] = A[M,K] @ Bt[N,K]^T (+bias)(+C)(ReLU)
// MR=8: BM=256, MR=4: BM=128.  BN=256 always. 512 threads = 8 waves (2x4).
// BK=32 per K-step; 4-slot LDS ring; prefetch distance 3; counted vmcnt.
// LDS tiles swizzled: element slot (8-elem group) ^= row&3, applied on the
// global source of global_load_lds AND on the ds_read address (rule #21).
// ===========================================================================
template<int MR, bool OUT_BF16, bool RELU, bool ACC>
__global__ __launch_bounds__(512, 2) void gemm_ring(
    const u16* __restrict__ A, int lda, const u16* __restrict__ Bt, int ldb,
    const float* __restrict__ bias, void* Cout, int ldc,
    int M, int N, int K)
{
  constexpr int BM = MR * 32;            // 256 or 128
  constexpr int SLOT = (BM + 256) * 32;  // elements per ring slot (A then B)
  constexpr int LPG = (MR == 8) ? 4 : 3; // global_load_lds per thread per step
  __shared__ u16 ring[4 * SLOT];         // 128 KB (MR=8) / 96 KB (MR=4)

  const int tid = threadIdx.x;
  const int lane = tid & 63, wave = tid >> 6;
  const int wm = wave >> 2, wn = wave & 3;
  const int m0 = blockIdx.x * BM, n0 = blockIdx.y * 256;

  // ---- staging thread-constants (pre-swizzled global sources) ----
  const int cA0 = tid;                    // A chunk 0 (rows 0..127)
  const int rA0 = cA0 >> 2;
  const u16* gA0 = A + (size_t)(m0 + rA0) * lda + (((cA0 & 3) ^ (rA0 & 3)) * 8);
  const int cA1 = tid + 512;              // A chunk 1 (MR==8 only)
  const int rA1 = cA1 >> 2;
  const u16* gA1 = A + (size_t)(m0 + (MR == 8 ? rA1 : 0)) * lda + (((cA1 & 3) ^ (rA1 & 3)) * 8);
  const int cB0 = tid, cB1 = tid + 512;
  const int rB0 = cB0 >> 2, rB1 = cB1 >> 2;
  const u16* gB0 = Bt + (size_t)(n0 + rB0) * ldb + (((cB0 & 3) ^ (rB0 & 3)) * 8);
  const u16* gB1 = Bt + (size_t)(n0 + rB1) * ldb + (((cB1 & 3) ^ (rB1 & 3)) * 8);

  const int NK = K >> 5;                  // K-steps of 32

  auto STAGE = [&](int s) {
    u16* Sb = &ring[(s & 3) * SLOT];
    const int ko = s * 32;
    gload_lds16(gA0 + ko, Sb + cA0 * 8);
    if constexpr (MR == 8) gload_lds16(gA1 + ko, Sb + cA1 * 8);
    gload_lds16(gB0 + ko, Sb + BM * 32 + cB0 * 8);
    gload_lds16(gB1 + ko, Sb + BM * 32 + cB1 * 8);
  };
  auto WAITV = [&](int ahead) {
    if (ahead >= 2) {
      if constexpr (MR == 8) asm volatile("s_waitcnt vmcnt(8)" ::: "memory");
      else                   asm volatile("s_waitcnt vmcnt(6)" ::: "memory");
    } else if (ahead == 1) {
      if constexpr (MR == 8) asm volatile("s_waitcnt vmcnt(4)" ::: "memory");
      else                   asm volatile("s_waitcnt vmcnt(3)" ::: "memory");
    } else {
      asm volatile("s_waitcnt vmcnt(0)" ::: "memory");
    }
    __builtin_amdgcn_sched_barrier(0);
  };

  // ---- fragment-read lane constants (swizzled ds_read offsets) ----
  const int fr = lane & 15, g = lane >> 4;
  const int sw = g ^ (fr & 3);            // swizzled 8-elem slot
  const int foff = fr * 32 + sw * 8;      // element offset within tile row group

  f32x4 acc[MR][4];
  #pragma unroll
  for (int m = 0; m < MR; m++)
    #pragma unroll
    for (int n = 0; n < 4; n++) acc[m][n] = f32x4{0.f, 0.f, 0.f, 0.f};

  // ---- prologue: stage 3 K-steps ahead ----
  for (int i = 0; i < 3; ++i) if (i < NK) STAGE(i);
  {
    int im = (NK - 1 < 2) ? NK - 1 : 2;
    WAITV(im);
  }
  __builtin_amdgcn_s_barrier();
  __builtin_amdgcn_sched_barrier(0);

  for (int s = 0; s < NK; ++s) {
    const u16* Sb = &ring[(s & 3) * SLOT];
    const u16* As = Sb;
    const u16* Bs = Sb + BM * 32;

    // ---------------- phase 0 : B all + A first half ----------------
    bf16x8 bf[4];
    #pragma unroll
    for (int n = 0; n < 4; n++)
      bf[n] = *(const bf16x8*)(Bs + (wn * 64 + n * 16) * 32 + foff);
    {
      bf16x8 af[MR / 2];
      #pragma unroll
      for (int m = 0; m < MR / 2; m++)
        af[m] = *(const bf16x8*)(As + (wm * (MR * 16) + m * 16) * 32 + foff);
      if (s + 3 < NK) STAGE(s + 3);
      __builtin_amdgcn_s_barrier();
      asm volatile("s_waitcnt lgkmcnt(0)" ::: "memory");
      __builtin_amdgcn_sched_barrier(0);
      __builtin_amdgcn_s_setprio(1);
      #pragma unroll
      for (int m = 0; m < MR / 2; m++)
        #pragma unroll
        for (int n = 0; n < 4; n++)
          acc[m][n] = mfma_16x16x32(af[m], bf[n], acc[m][n]);
      __builtin_amdgcn_s_setprio(0);
      __builtin_amdgcn_s_barrier();
      __builtin_amdgcn_sched_barrier(0);
    }
    // ---------------- phase 1 : A second half ----------------
    {
      bf16x8 af[MR / 2];
      #pragma unroll
      for (int m = 0; m < MR / 2; m++)
        af[m] = *(const bf16x8*)(As + (wm * (MR * 16) + (m + MR / 2) * 16) * 32 + foff);
      __builtin_amdgcn_s_barrier();
      asm volatile("s_waitcnt lgkmcnt(0)" ::: "memory");
      __builtin_amdgcn_sched_barrier(0);
      __builtin_amdgcn_s_setprio(1);
      #pragma unroll
      for (int m = 0; m < MR / 2; m++)
        #pragma unroll
        for (int n = 0; n < 4; n++)
          acc[m + MR / 2][n] = mfma_16x16x32(af[m], bf[n], acc[m + MR / 2][n]);
      __builtin_amdgcn_s_setprio(0);
      {
        int im = (s + 3 < NK - 1) ? s + 3 : NK - 1;
        WAITV(im - (s + 1));
      }
      __builtin_amdgcn_s_barrier();
      __builtin_amdgcn_sched_barrier(0);
    }
  }

  // ---- epilogue ----
  #pragma unroll
  for (int n = 0; n < 4; n++) {
    const int gcol = n0 + wn * 64 + n * 16 + fr;
    const float bv = bias ? bias[gcol] : 0.f;
    #pragma unroll
    for (int m = 0; m < MR; m++) {
      #pragma unroll
      for (int r = 0; r < 4; r++) {
        const int grow = m0 + wm * (MR * 16) + m * 16 + g * 4 + r;
        float v = acc[m][n][r] + bv;
        if (ACC) v += bf2f(((const u16*)Cout)[(size_t)grow * ldc + gcol]);
        if (RELU) v = fmaxf(v, 0.f);
        if (OUT_BF16) ((u16*)Cout)[(size_t)grow * ldc + gcol] = f2bf(v);
        else         ((float*)Cout)[(size_t)grow * ldc + gcol] = v;
      }
    }
  }
}

// ---------------------------------------------------------------------------
// Small GEMM (kept for M=400 K/V projections): 128x128 tile, BK=32.
// ---------------------------------------------------------------------------
template<bool OUT_BF16>
__global__ __launch_bounds__(256, 2) void gemm_bt(
    const u16* __restrict__ A, int lda, const u16* __restrict__ Bt, int ldb,
    const float* __restrict__ bias, void* Cout, int ldc,
    int M, int N, int K)
{
  __shared__ u16 ldsA[128 * 32];
  __shared__ u16 ldsB[128 * 32];

  const int tid = threadIdx.x;
  const int lane = tid & 63, wave = tid >> 6;
  const int wr = wave >> 1, wc = wave & 1;
  const int m0 = blockIdx.x * 128, n0 = blockIdx.y * 128;

  const int c0 = tid, c1 = tid + 256;
  const int ar0 = c0 >> 2, ak0 = (c0 & 3) * 8;
  const int ar1 = c1 >> 2, ak1 = (c1 & 3) * 8;

  const bool av0 = (m0 + ar0) < M;
  const bool av1 = (m0 + ar1) < M;
  const u16* Ag0 = A + (size_t)(m0 + ar0) * lda + ak0;
  const u16* Ag1 = A + (size_t)(m0 + ar1) * lda + ak1;
  const u16* Bg0 = Bt + (size_t)(n0 + ar0) * ldb + ak0;
  const u16* Bg1 = Bt + (size_t)(n0 + ar1) * ldb + ak1;

  f32x4 acc[4][4] = {};
  const int fr = lane & 15, fo = (lane >> 4) * 8;

  for (int k0 = 0; k0 < K; k0 += 32) {
    if (av0) gload_lds16(Ag0 + k0, &ldsA[c0 * 8]);
    if (av1) gload_lds16(Ag1 + k0, &ldsA[c1 * 8]);
    gload_lds16(Bg0 + k0, &ldsB[c0 * 8]);
    gload_lds16(Bg1 + k0, &ldsB[c1 * 8]);
    asm volatile("s_waitcnt vmcnt(0)" ::: "memory");
    __syncthreads();

    bf16x8 af[4], bfr[4];
    #pragma unroll
    for (int m = 0; m < 4; m++)
      af[m] = *(const bf16x8*)&ldsA[(wr * 64 + m * 16 + fr) * 32 + fo];
    #pragma unroll
    for (int n = 0; n < 4; n++)
      bfr[n] = *(const bf16x8*)&ldsB[(wc * 64 + n * 16 + fr) * 32 + fo];
    #pragma unroll
    for (int m = 0; m < 4; m++)
      #pragma unroll
      for (int n = 0; n < 4; n++)
        acc[m][n] = mfma_16x16x32(af[m], bfr[n], acc[m][n]);
    __syncthreads();
  }

  const int g = lane >> 4;
  #pragma unroll
  for (int m = 0; m < 4; m++) {
    #pragma unroll
    for (int n = 0; n < 4; n++) {
      const int gcol = n0 + wc * 64 + n * 16 + fr;
      const float bv = bias ? bias[gcol] : 0.f;
      #pragma unroll
      for (int r = 0; r < 4; r++) {
        const int grow = m0 + wr * 64 + m * 16 + g * 4 + r;
        if (grow < M) {
          float v = acc[m][n][r] + bv;
          if (OUT_BF16) ((u16*)Cout)[(size_t)grow * ldc + gcol] = f2bf(v);
          else         ((float*)Cout)[(size_t)grow * ldc + gcol] = v;
        }
      }
    }
  }
}

// ---------------------------------------------------------------------------
// Weight transpose+convert: src f32 [K][N] -> dst bf16 [N][K]
// ---------------------------------------------------------------------------
__global__ void wconv_t(const float* __restrict__ src, u16* __restrict__ dst,
                        int K, int N)
{
  __shared__ float tile[32][33];
  const int n0 = blockIdx.x * 32, k0 = blockIdx.y * 32;
  const int tx = threadIdx.x, ty = threadIdx.y;
  #pragma unroll
  for (int i = 0; i < 4; i++)
    tile[ty + i * 8][tx] = src[(size_t)(k0 + ty + i * 8) * N + n0 + tx];
  __syncthreads();
  #pragma unroll
  for (int i = 0; i < 4; i++)
    dst[(size_t)(n0 + ty + i * 8) * K + k0 + tx] = f2bf(tile[tx][ty + i * 8]);
}

// ---------------------------------------------------------------------------
// Positional encoding add
// ---------------------------------------------------------------------------
__global__ __launch_bounds__(256) void pe_video_k(const float* __restrict__ video,
                                                  float* __restrict__ vf32,
                                                  u16* __restrict__ vbf)
{
  const int r = blockIdx.x;
  const int s = r & 2047;
  const int d0 = threadIdx.x * 4;
  const size_t base = (size_t)r * 1024 + d0;
  float4 v = *(const float4*)&video[base];
  const float coef = -9.210340371976184f / 1024.f;
  float o[4];
  float in[4] = {v.x, v.y, v.z, v.w};
  #pragma unroll
  for (int i = 0; i < 4; i++) {
    int d = d0 + i;
    int j = d >> 1;
    float dv = expf((float)(2 * j) * coef);
    float arg = (float)s * dv;
    float pe = (d & 1) ? cosf(arg) : sinf(arg);
    o[i] = in[i] + pe;
  }
  *(float4*)&vf32[base] = make_float4(o[0], o[1], o[2], o[3]);
  uint2 pk;
  pk.x = (uint32_t)f2bf(o[0]) | ((uint32_t)f2bf(o[1]) << 16);
  pk.y = (uint32_t)f2bf(o[2]) | ((uint32_t)f2bf(o[3]) << 16);
  *(uint2*)&vbf[base] = pk;
}

__global__ __launch_bounds__(128) void pe_text_k(const float* __restrict__ text,
                                                 u16* __restrict__ tbf)
{
  const int r = blockIdx.x;
  const int s = r % 100;
  const int d0 = threadIdx.x * 4;
  const size_t base = (size_t)r * 512 + d0;
  float4 v = *(const float4*)&text[base];
  const float coef = -9.210340371976184f / 512.f;
  float o[4];
  float in[4] = {v.x, v.y, v.z, v.w};
  #pragma unroll
  for (int i = 0; i < 4; i++) {
    int d = d0 + i;
    int j = d >> 1;
    float dv = expf((float)(2 * j) * coef);
    float arg = (float)s * dv;
    float pe = (d & 1) ? cosf(arg) : sinf(arg);
    o[i] = in[i] + pe;
  }
  uint2 pk;
  pk.x = (uint32_t)f2bf(o[0]) | ((uint32_t)f2bf(o[1]) << 16);
  pk.y = (uint32_t)f2bf(o[2]) | ((uint32_t)f2bf(o[3]) << 16);
  *(uint2*)&tbf[base] = pk;
}

// ---------------------------------------------------------------------------
// LayerNorm with residual: x = LN(x + delta)*g+b ; delta bf16
// ---------------------------------------------------------------------------
__global__ __launch_bounds__(256) void ln_res(float* __restrict__ x,
                                              const u16* __restrict__ delta,
                                              const float* __restrict__ gamma,
                                              const float* __restrict__ beta,
                                              u16* __restrict__ xbf)
{
  const int row = blockIdx.x;
  const size_t base = (size_t)row * 1024;
  const int t = threadIdx.x;
  const int d0 = t * 4;
  float4 xv = *(const float4*)&x[base + d0];
  uint2 dv2 = *(const uint2*)&delta[base + d0];
  float v0 = xv.x + bf2f((u16)(dv2.x & 0xFFFF));
  float v1 = xv.y + bf2f((u16)(dv2.x >> 16));
  float v2 = xv.z + bf2f((u16)(dv2.y & 0xFFFF));
  float v3 = xv.w + bf2f((u16)(dv2.y >> 16));
  float s = v0 + v1 + v2 + v3;
  float q = v0 * v0 + v1 * v1 + v2 * v2 + v3 * v3;
  #pragma unroll
  for (int d = 32; d >= 1; d >>= 1) { s += __shfl_xor(s, d); q += __shfl_xor(q, d); }
  __shared__ float red[8];
  const int lane = t & 63, w = t >> 6;
  if (lane == 0) { red[w] = s; red[4 + w] = q; }
  __syncthreads();
  float S = red[0] + red[1] + red[2] + red[3];
  float Qs = red[4] + red[5] + red[6] + red[7];
  const float mu = S * (1.f / 1024.f);
  const float var = Qs * (1.f / 1024.f) - mu * mu;
  const float rs = rsqrtf(var + 1e-5f);
  float4 gv = *(const float4*)&gamma[d0];
  float4 bv = *(const float4*)&beta[d0];
  float o0 = (v0 - mu) * rs * gv.x + bv.x;
  float o1 = (v1 - mu) * rs * gv.y + bv.y;
  float o2 = (v2 - mu) * rs * gv.z + bv.z;
  float o3 = (v3 - mu) * rs * gv.w + bv.w;
  *(float4*)&x[base + d0] = make_float4(o0, o1, o2, o3);
  uint2 pk;
  pk.x = (uint32_t)f2bf(o0) | ((uint32_t)f2bf(o1) << 16);
  pk.y = (uint32_t)f2bf(o2) | ((uint32_t)f2bf(o3) << 16);
  *(uint2*)&xbf[base + d0] = pk;
}

// ---------------------------------------------------------------------------
// Cross attention: per block = 64 q-rows x one (b,h).
// ---------------------------------------------------------------------------
#define A_ST 100
#define A_STP 128
#define A_DK 64
#define A_DM 1024
#define A_SQ 2048

__global__ __launch_bounds__(256) void attn_kernel(
    const u16* __restrict__ Q, const u16* __restrict__ Kb,
    const u16* __restrict__ Vb, const int* __restrict__ mask,
    u16* __restrict__ Out)
{
  __shared__ u16 ldsK[A_STP * A_DK];
  __shared__ u16 ldsVt[A_DK * A_STP];
  __shared__ u16 ldsP[64 * A_STP];
  __shared__ float smadd[A_STP];

  const int tid = threadIdx.x, lane = tid & 63, w = tid >> 6;
  const int qb = blockIdx.x, bh = blockIdx.y;
  const int b = bh >> 4, h = bh & 15;

  for (int c = tid; c < A_STP * A_DK / 8; c += 256) {
    int j = c >> 3, kc = (c & 7) * 8;
    uint4 val = make_uint4(0u, 0u, 0u, 0u);
    if (j < A_ST) val = *(const uint4*)&Kb[((size_t)(b * A_ST + j)) * A_DM + h * A_DK + kc];
    *(uint4*)&ldsK[j * A_DK + kc] = val;
  }
  for (int idx = tid; idx < A_DK * A_STP; idx += 256) {
    int d = idx >> 7, j = idx & 127;
    u16 v = 0;
    if (j < A_ST) v = Vb[((size_t)(b * A_ST + j)) * A_DM + h * A_DK + d];
    ldsVt[d * A_STP + j] = v;
  }
  for (int j = tid; j < A_STP; j += 256)
    smadd[j] = (j < A_ST && mask[b * A_ST + j] != 0) ? 0.f : -1e30f;
  for (int idx = tid; idx < 64 * A_STP; idx += 256) ldsP[idx] = 0;

  const int fr = lane & 15, g = lane >> 4, fo = g * 8;

  const size_t qrow = (size_t)(b * A_SQ + qb * 64 + w * 16 + fr) * A_DM + h * A_DK;
  bf16x8 qf0 = *(const bf16x8*)&Q[qrow + fo];
  bf16x8 qf1 = *(const bf16x8*)&Q[qrow + 32 + fo];

  __syncthreads();

  float sc[7][4];
  #pragma unroll
  for (int t = 0; t < 7; t++) {
    f32x4 a = {};
    bf16x8 kf0 = *(const bf16x8*)&ldsK[(t * 16 + fr) * A_DK + fo];
    bf16x8 kf1 = *(const bf16x8*)&ldsK[(t * 16 + fr) * A_DK + 32 + fo];
    a = mfma_16x16x32(qf0, kf0, a);
    a = mfma_16x16x32(qf1, kf1, a);
    #pragma unroll
    for (int r = 0; r < 4; r++)
      sc[t][r] = a[r] * 0.125f + smadd[t * 16 + fr];
  }

  #pragma unroll
  for (int r = 0; r < 4; r++) {
    float m = sc[0][r];
    #pragma unroll
    for (int t = 1; t < 7; t++) m = fmaxf(m, sc[t][r]);
    #pragma unroll
    for (int d = 8; d >= 1; d >>= 1) m = fmaxf(m, __shfl_xor(m, d));
    float ssum = 0.f;
    #pragma unroll
    for (int t = 0; t < 7; t++) { float p = __expf(sc[t][r] - m); sc[t][r] = p; ssum += p; }
    #pragma unroll
    for (int d = 8; d >= 1; d >>= 1) ssum += __shfl_xor(ssum, d);
    float is = 1.f / ssum;
    #pragma unroll
    for (int t = 0; t < 7; t++)
      ldsP[(w * 16 + g * 4 + r) * A_STP + t * 16 + fr] = f2bf(sc[t][r] * is);
  }
  __syncthreads();

  bf16x8 pa[4];
  #pragma unroll
  for (int kk = 0; kk < 4; kk++)
    pa[kk] = *(const bf16x8*)&ldsP[(w * 16 + fr) * A_STP + kk * 32 + fo];
  #pragma unroll
  for (int nt = 0; nt < 4; nt++) {
    f32x4 a = {};
    #pragma unroll
    for (int kk = 0; kk < 4; kk++) {
      bf16x8 vf = *(const bf16x8*)&ldsVt[(nt * 16 + fr) * A_STP + kk * 32 + fo];
      a = mfma_16x16x32(pa[kk], vf, a);
    }
    #pragma unroll
    for (int r = 0; r < 4; r++) {
      size_t orow = (size_t)(b * A_SQ + qb * 64 + w * 16 + g * 4 + r) * A_DM + h * A_DK + nt * 16 + fr;
      Out[orow] = f2bf(a[r]);
    }
  }
}

// ---------------------------------------------------------------------------
extern "C" void kernel_launch(void* const* d_in, const int* in_sizes, int n_in,
                              void* d_out, int out_size, void* d_ws, size_t ws_size,
                              hipStream_t stream) {
  const float* video = (const float*)d_in[0];
  const float* text  = (const float*)d_in[1];
  const int*   text_mask = (const int*)d_in[2];
  const float* Wq_w = (const float*)d_in[3];
  const float* Wq_b = (const float*)d_in[4];
  const float* Wk_w = (const float*)d_in[5];
  const float* Wk_b = (const float*)d_in[6];
  const float* Wv_w = (const float*)d_in[7];
  const float* Wv_b = (const float*)d_in[8];
  const float* Wo_w = (const float*)d_in[9];
  const float* Wo_b = (const float*)d_in[10];
  const float* fc1_w = (const float*)d_in[11];
  const float* fc1_b = (const float*)d_in[12];
  const float* fc2_w = (const float*)d_in[13];
  const float* fc2_b = (const float*)d_in[14];
  const float* n2_g = (const float*)d_in[15];
  const float* n2_b = (const float*)d_in[16];
  const float* n3_g = (const float*)d_in[17];
  const float* n3_b = (const float*)d_in[18];

  char* ws = (char*)d_ws;
  size_t off = 0;
  auto alloc = [&](size_t bytes) {
    char* p = ws + off;
    off += (bytes + 255) & ~(size_t)255;
    return p;
  };
  u16* vbf = (u16*)alloc((size_t)8192 * 1024 * 2);
  u16* tbf = (u16*)alloc((size_t)400 * 512 * 2);
  u16* wqT = (u16*)alloc((size_t)1024 * 1024 * 2);
  u16* wkT = (u16*)alloc((size_t)1024 * 512 * 2);
  u16* wvT = (u16*)alloc((size_t)1024 * 512 * 2);
  u16* woT = (u16*)alloc((size_t)1024 * 1024 * 2);
  u16* f1T = (u16*)alloc((size_t)4096 * 1024 * 2);
  u16* f2T = (u16*)alloc((size_t)1024 * 4096 * 2);
  char* S = alloc((size_t)35192832);
  u16* qbf  = (u16*)S;
  u16* kbf  = (u16*)(S + 16777216);
  u16* vvbf = (u16*)(S + 16777216 + 819200);
  u16* abf  = (u16*)(S + 16777216 + 1638400);
  u16* h1c  = (u16*)S;
  u16* dbf = (u16*)alloc((size_t)8192 * 1024 * 2);

  float* vf32 = (float*)d_out;

  pe_video_k<<<8192, 256, 0, stream>>>(video, vf32, vbf);
  pe_text_k<<<400, 128, 0, stream>>>(text, tbf);

  dim3 tb(32, 8, 1);
  for (int l = 0; l < 4; ++l) {
    wconv_t<<<dim3(32, 32), tb, 0, stream>>>(Wq_w + (size_t)l * 1024 * 1024, wqT, 1024, 1024);
    wconv_t<<<dim3(32, 16), tb, 0, stream>>>(Wk_w + (size_t)l * 512 * 1024, wkT, 512, 1024);
    wconv_t<<<dim3(32, 16), tb, 0, stream>>>(Wv_w + (size_t)l * 512 * 1024, wvT, 512, 1024);
    wconv_t<<<dim3(32, 32), tb, 0, stream>>>(Wo_w + (size_t)l * 1024 * 1024, woT, 1024, 1024);
    wconv_t<<<dim3(128, 32), tb, 0, stream>>>(fc1_w + (size_t)l * 1024 * 4096, f1T, 1024, 4096);
    wconv_t<<<dim3(32, 128), tb, 0, stream>>>(fc2_w + (size_t)l * 4096 * 1024, f2T, 4096, 1024);

    // Q = vbf @ wqT : flat ring kernel (128x256 tiles, grid 64x4 = 256)
    gemm_ring<4, true, false, false><<<dim3(64, 4), 512, 0, stream>>>(
        vbf, 1024, wqT, 1024, Wq_b + l * 1024, qbf, 1024, 8192, 1024, 1024);
    gemm_bt<true><<<dim3(4, 8), 256, 0, stream>>>(
        tbf, 512, wkT, 512, Wk_b + l * 1024, kbf, 1024, 400, 1024, 512);
    gemm_bt<true><<<dim3(4, 8), 256, 0, stream>>>(
        tbf, 512, wvT, 512, Wv_b + l * 1024, vvbf, 1024, 400, 1024, 512);
    attn_kernel<<<dim3(32, 64), 256, 0, stream>>>(qbf, kbf, vvbf, text_mask, abf);
    gemm_ring<4, true, false, false><<<dim3(64, 4), 512, 0, stream>>>(
        abf, 1024, woT, 1024, Wo_b + l * 1024, dbf, 1024, 8192, 1024, 1024);
    ln_res<<<8192, 256, 0, stream>>>(vf32, dbf, n2_g + l * 1024, n2_b + l * 1024, vbf);

    for (int c = 0; c < 2; ++c) {
      // FF1 chunk: big ring kernel (256x256 tiles, grid 32x8 = 256)
      gemm_ring<8, true, true, false><<<dim3(32, 8), 512, 0, stream>>>(
          vbf, 1024, f1T + (size_t)c * 2048 * 1024, 1024,
          fc1_b + l * 4096 + c * 2048, h1c, 2048, 8192, 2048, 1024);
      // FF2 chunk: flat ring kernel (grid 64x4 = 256), c=1 accumulates
      if (c == 0)
        gemm_ring<4, true, false, false><<<dim3(64, 4), 512, 0, stream>>>(
            h1c, 2048, f2T + (size_t)c * 2048, 4096,
            fc2_b + l * 1024, dbf, 1024, 8192, 1024, 2048);
      else
        gemm_ring<4, true, false, true><<<dim3(64, 4), 512, 0, stream>>>(
            h1c, 2048, f2T + (size_t)c * 2048, 4096,
            nullptr, dbf, 1024, 8192, 1024, 2048);
    }
    ln_res<<<8192, 256, 0, stream>>>(vf32, dbf, n3_g + l * 1024, n3_b + l * 1024, vbf);
  }
}

// Round 4
// 1394.569 us; speedup vs baseline: 1.2189x; 1.1100x over previous
//
#include <hip/hip_runtime.h>
#include <cstdint>
#include <cstddef>

typedef unsigned short u16;
typedef __attribute__((ext_vector_type(8))) __bf16 bf16x8;
typedef __attribute__((ext_vector_type(4))) float f32x4;

__device__ __forceinline__ f32x4 mfma_16x16x32(bf16x8 a, bf16x8 b, f32x4 c) {
  return __builtin_amdgcn_mfma_f32_16x16x32_bf16(a, b, c, 0, 0, 0);
}

__device__ __forceinline__ u16 f2bf(float f) {
  union { float f; uint32_t u; } c; c.f = f;
  uint32_t u = c.u + 0x7FFFu + ((c.u >> 16) & 1u);
  return (u16)(u >> 16);
}

__device__ __forceinline__ float bf2f(u16 x) {
  union { uint32_t u; float f; } c; c.u = ((uint32_t)x) << 16;
  return c.f;
}

__device__ __forceinline__ void gload_lds16(const void* g, void* l) {
  __builtin_amdgcn_global_load_lds(
      (__attribute__((address_space(1))) void*)(uintptr_t)g,
      (__attribute__((address_space(3))) void*)l, 16, 0, 0);
}

// ===========================================================================
// Deep-pipelined ring GEMM (unchanged from round 2 — passed).
// ===========================================================================
template<int MR, bool OUT_BF16, bool RELU, bool ACC>
__global__ __launch_bounds__(512, 2) void gemm_ring(
    const u16* __restrict__ A, int lda, const u16* __restrict__ Bt, int ldb,
    const float* __restrict__ bias, void* Cout, int ldc,
    int M, int N, int K)
{
  constexpr int BM = MR * 32;
  constexpr int SLOT = (BM + 256) * 32;
  __shared__ u16 ring[4 * SLOT];

  const int tid = threadIdx.x;
  const int lane = tid & 63, wave = tid >> 6;
  const int wm = wave >> 2, wn = wave & 3;
  const int m0 = blockIdx.x * BM, n0 = blockIdx.y * 256;

  const int cA0 = tid;
  const int rA0 = cA0 >> 2;
  const u16* gA0 = A + (size_t)(m0 + rA0) * lda + (((cA0 & 3) ^ (rA0 & 3)) * 8);
  const int cA1 = tid + 512;
  const int rA1 = cA1 >> 2;
  const u16* gA1 = A + (size_t)(m0 + (MR == 8 ? rA1 : 0)) * lda + (((cA1 & 3) ^ (rA1 & 3)) * 8);
  const int cB0 = tid, cB1 = tid + 512;
  const int rB0 = cB0 >> 2, rB1 = cB1 >> 2;
  const u16* gB0 = Bt + (size_t)(n0 + rB0) * ldb + (((cB0 & 3) ^ (rB0 & 3)) * 8);
  const u16* gB1 = Bt + (size_t)(n0 + rB1) * ldb + (((cB1 & 3) ^ (rB1 & 3)) * 8);

  const int NK = K >> 5;

  auto STAGE = [&](int s) {
    u16* Sb = &ring[(s & 3) * SLOT];
    const int ko = s * 32;
    gload_lds16(gA0 + ko, Sb + cA0 * 8);
    if constexpr (MR == 8) gload_lds16(gA1 + ko, Sb + cA1 * 8);
    gload_lds16(gB0 + ko, Sb + BM * 32 + cB0 * 8);
    gload_lds16(gB1 + ko, Sb + BM * 32 + cB1 * 8);
  };
  auto WAITV = [&](int ahead) {
    if (ahead >= 2) {
      if constexpr (MR == 8) asm volatile("s_waitcnt vmcnt(8)" ::: "memory");
      else                   asm volatile("s_waitcnt vmcnt(6)" ::: "memory");
    } else if (ahead == 1) {
      if constexpr (MR == 8) asm volatile("s_waitcnt vmcnt(4)" ::: "memory");
      else                   asm volatile("s_waitcnt vmcnt(3)" ::: "memory");
    } else {
      asm volatile("s_waitcnt vmcnt(0)" ::: "memory");
    }
    __builtin_amdgcn_sched_barrier(0);
  };

  const int fr = lane & 15, g = lane >> 4;
  const int sw = g ^ (fr & 3);
  const int foff = fr * 32 + sw * 8;

  f32x4 acc[MR][4];
  #pragma unroll
  for (int m = 0; m < MR; m++)
    #pragma unroll
    for (int n = 0; n < 4; n++) acc[m][n] = f32x4{0.f, 0.f, 0.f, 0.f};

  for (int i = 0; i < 3; ++i) if (i < NK) STAGE(i);
  {
    int im = (NK - 1 < 2) ? NK - 1 : 2;
    WAITV(im);
  }
  __builtin_amdgcn_s_barrier();
  __builtin_amdgcn_sched_barrier(0);

  for (int s = 0; s < NK; ++s) {
    const u16* Sb = &ring[(s & 3) * SLOT];
    const u16* As = Sb;
    const u16* Bs = Sb + BM * 32;

    bf16x8 bf[4];
    #pragma unroll
    for (int n = 0; n < 4; n++)
      bf[n] = *(const bf16x8*)(Bs + (wn * 64 + n * 16) * 32 + foff);
    {
      bf16x8 af[MR / 2];
      #pragma unroll
      for (int m = 0; m < MR / 2; m++)
        af[m] = *(const bf16x8*)(As + (wm * (MR * 16) + m * 16) * 32 + foff);
      if (s + 3 < NK) STAGE(s + 3);
      __builtin_amdgcn_s_barrier();
      asm volatile("s_waitcnt lgkmcnt(0)" ::: "memory");
      __builtin_amdgcn_sched_barrier(0);
      __builtin_amdgcn_s_setprio(1);
      #pragma unroll
      for (int m = 0; m < MR / 2; m++)
        #pragma unroll
        for (int n = 0; n < 4; n++)
          acc[m][n] = mfma_16x16x32(af[m], bf[n], acc[m][n]);
      __builtin_amdgcn_s_setprio(0);
      __builtin_amdgcn_s_barrier();
      __builtin_amdgcn_sched_barrier(0);
    }
    {
      bf16x8 af[MR / 2];
      #pragma unroll
      for (int m = 0; m < MR / 2; m++)
        af[m] = *(const bf16x8*)(As + (wm * (MR * 16) + (m + MR / 2) * 16) * 32 + foff);
      __builtin_amdgcn_s_barrier();
      asm volatile("s_waitcnt lgkmcnt(0)" ::: "memory");
      __builtin_amdgcn_sched_barrier(0);
      __builtin_amdgcn_s_setprio(1);
      #pragma unroll
      for (int m = 0; m < MR / 2; m++)
        #pragma unroll
        for (int n = 0; n < 4; n++)
          acc[m + MR / 2][n] = mfma_16x16x32(af[m], bf[n], acc[m + MR / 2][n]);
      __builtin_amdgcn_s_setprio(0);
      {
        int im = (s + 3 < NK - 1) ? s + 3 : NK - 1;
        WAITV(im - (s + 1));
      }
      __builtin_amdgcn_s_barrier();
      __builtin_amdgcn_sched_barrier(0);
    }
  }

  #pragma unroll
  for (int n = 0; n < 4; n++) {
    const int gcol = n0 + wn * 64 + n * 16 + fr;
    const float bv = bias ? bias[gcol] : 0.f;
    #pragma unroll
    for (int m = 0; m < MR; m++) {
      #pragma unroll
      for (int r = 0; r < 4; r++) {
        const int grow = m0 + wm * (MR * 16) + m * 16 + g * 4 + r;
        float v = acc[m][n][r] + bv;
        if (ACC) v += bf2f(((const u16*)Cout)[(size_t)grow * ldc + gcol]);
        if (RELU) v = fmaxf(v, 0.f);
        if (OUT_BF16) ((u16*)Cout)[(size_t)grow * ldc + gcol] = f2bf(v);
        else         ((float*)Cout)[(size_t)grow * ldc + gcol] = v;
      }
    }
  }
}

// ---------------------------------------------------------------------------
// Small GEMM (M=400 K/V projections): 128x128 tile, BK=32.
// TRANS=true: store C transposed into vtb[((b*16+h)*64+d)*128 + j]
//   where grow = b*100+j (M=400), gcol = h*64+d (N=1024).
// ---------------------------------------------------------------------------
template<bool TRANS>
__global__ __launch_bounds__(256, 2) void gemm_bt(
    const u16* __restrict__ A, int lda, const u16* __restrict__ Bt, int ldb,
    const float* __restrict__ bias, u16* Cout, int ldc,
    int M, int N, int K)
{
  __shared__ u16 ldsA[128 * 32];
  __shared__ u16 ldsB[128 * 32];

  const int tid = threadIdx.x;
  const int lane = tid & 63, wave = tid >> 6;
  const int wr = wave >> 1, wc = wave & 1;
  const int m0 = blockIdx.x * 128, n0 = blockIdx.y * 128;

  const int c0 = tid, c1 = tid + 256;
  const int ar0 = c0 >> 2, ak0 = (c0 & 3) * 8;
  const int ar1 = c1 >> 2, ak1 = (c1 & 3) * 8;

  const bool av0 = (m0 + ar0) < M;
  const bool av1 = (m0 + ar1) < M;
  const u16* Ag0 = A + (size_t)(m0 + ar0) * lda + ak0;
  const u16* Ag1 = A + (size_t)(m0 + ar1) * lda + ak1;
  const u16* Bg0 = Bt + (size_t)(n0 + ar0) * ldb + ak0;
  const u16* Bg1 = Bt + (size_t)(n0 + ar1) * ldb + ak1;

  f32x4 acc[4][4] = {};
  const int fr = lane & 15, fo = (lane >> 4) * 8;

  for (int k0 = 0; k0 < K; k0 += 32) {
    if (av0) gload_lds16(Ag0 + k0, &ldsA[c0 * 8]);
    if (av1) gload_lds16(Ag1 + k0, &ldsA[c1 * 8]);
    gload_lds16(Bg0 + k0, &ldsB[c0 * 8]);
    gload_lds16(Bg1 + k0, &ldsB[c1 * 8]);
    asm volatile("s_waitcnt vmcnt(0)" ::: "memory");
    __syncthreads();

    bf16x8 af[4], bfr[4];
    #pragma unroll
    for (int m = 0; m < 4; m++)
      af[m] = *(const bf16x8*)&ldsA[(wr * 64 + m * 16 + fr) * 32 + fo];
    #pragma unroll
    for (int n = 0; n < 4; n++)
      bfr[n] = *(const bf16x8*)&ldsB[(wc * 64 + n * 16 + fr) * 32 + fo];
    #pragma unroll
    for (int m = 0; m < 4; m++)
      #pragma unroll
      for (int n = 0; n < 4; n++)
        acc[m][n] = mfma_16x16x32(af[m], bfr[n], acc[m][n]);
    __syncthreads();
  }

  const int g = lane >> 4;
  #pragma unroll
  for (int m = 0; m < 4; m++) {
    #pragma unroll
    for (int n = 0; n < 4; n++) {
      const int gcol = n0 + wc * 64 + n * 16 + fr;
      const float bv = bias[gcol];
      #pragma unroll
      for (int r = 0; r < 4; r++) {
        const int grow = m0 + wr * 64 + m * 16 + g * 4 + r;
        if (grow < M) {
          float v = acc[m][n][r] + bv;
          if (TRANS) {
            int bb = grow / 100, jj = grow - bb * 100;
            int h = gcol >> 6, d = gcol & 63;
            Cout[(size_t)(((bb * 16 + h) * 64 + d)) * 128 + jj] = f2bf(v);
          } else {
            Cout[(size_t)grow * ldc + gcol] = f2bf(v);
          }
        }
      }
    }
  }
}

// ---------------------------------------------------------------------------
// Weight transpose+convert: src f32 [K][N] -> dst bf16 [N][K]
// ---------------------------------------------------------------------------
__global__ void wconv_t(const float* __restrict__ src, u16* __restrict__ dst,
                        int K, int N)
{
  __shared__ float tile[32][33];
  const int n0 = blockIdx.x * 32, k0 = blockIdx.y * 32;
  const int tx = threadIdx.x, ty = threadIdx.y;
  #pragma unroll
  for (int i = 0; i < 4; i++)
    tile[ty + i * 8][tx] = src[(size_t)(k0 + ty + i * 8) * N + n0 + tx];
  __syncthreads();
  #pragma unroll
  for (int i = 0; i < 4; i++)
    dst[(size_t)(n0 + ty + i * 8) * K + k0 + tx] = f2bf(tile[tx][ty + i * 8]);
}

// ---------------------------------------------------------------------------
// Positional encoding add -> bf16 only
// ---------------------------------------------------------------------------
__global__ __launch_bounds__(256) void pe_video_k(const float* __restrict__ video,
                                                  u16* __restrict__ vbf)
{
  const int r = blockIdx.x;
  const int s = r & 2047;
  const int d0 = threadIdx.x * 4;
  const size_t base = (size_t)r * 1024 + d0;
  float4 v = *(const float4*)&video[base];
  const float coef = -9.210340371976184f / 1024.f;
  float o[4];
  float in[4] = {v.x, v.y, v.z, v.w};
  #pragma unroll
  for (int i = 0; i < 4; i++) {
    int d = d0 + i;
    int j = d >> 1;
    float dv = expf((float)(2 * j) * coef);
    float arg = (float)s * dv;
    float pe = (d & 1) ? cosf(arg) : sinf(arg);
    o[i] = in[i] + pe;
  }
  uint2 pk;
  pk.x = (uint32_t)f2bf(o[0]) | ((uint32_t)f2bf(o[1]) << 16);
  pk.y = (uint32_t)f2bf(o[2]) | ((uint32_t)f2bf(o[3]) << 16);
  *(uint2*)&vbf[base] = pk;
}

__global__ __launch_bounds__(128) void pe_text_k(const float* __restrict__ text,
                                                 u16* __restrict__ tbf)
{
  const int r = blockIdx.x;
  const int s = r % 100;
  const int d0 = threadIdx.x * 4;
  const size_t base = (size_t)r * 512 + d0;
  float4 v = *(const float4*)&text[base];
  const float coef = -9.210340371976184f / 512.f;
  float o[4];
  float in[4] = {v.x, v.y, v.z, v.w};
  #pragma unroll
  for (int i = 0; i < 4; i++) {
    int d = d0 + i;
    int j = d >> 1;
    float dv = expf((float)(2 * j) * coef);
    float arg = (float)s * dv;
    float pe = (d & 1) ? cosf(arg) : sinf(arg);
    o[i] = in[i] + pe;
  }
  uint2 pk;
  pk.x = (uint32_t)f2bf(o[0]) | ((uint32_t)f2bf(o[1]) << 16);
  pk.y = (uint32_t)f2bf(o[2]) | ((uint32_t)f2bf(o[3]) << 16);
  *(uint2*)&tbf[base] = pk;
}

// ---------------------------------------------------------------------------
// LayerNorm, bf16 residual stream: x' = LN(x + delta)*g+b
// LAST: write f32 to fout (the model output).  else: write bf16 to xbf.
// ---------------------------------------------------------------------------
template<bool LAST>
__global__ __launch_bounds__(256) void ln2(const u16* __restrict__ xin,
                                           const u16* __restrict__ delta,
                                           const float* __restrict__ gamma,
                                           const float* __restrict__ beta,
                                           u16* __restrict__ xbf,
                                           float* __restrict__ fout)
{
  const int row = blockIdx.x;
  const size_t base = (size_t)row * 1024;
  const int t = threadIdx.x;
  const int d0 = t * 4;
  uint2 xv = *(const uint2*)&xin[base + d0];
  uint2 dv = *(const uint2*)&delta[base + d0];
  float v0 = bf2f((u16)(xv.x & 0xFFFF)) + bf2f((u16)(dv.x & 0xFFFF));
  float v1 = bf2f((u16)(xv.x >> 16))    + bf2f((u16)(dv.x >> 16));
  float v2 = bf2f((u16)(xv.y & 0xFFFF)) + bf2f((u16)(dv.y & 0xFFFF));
  float v3 = bf2f((u16)(xv.y >> 16))    + bf2f((u16)(dv.y >> 16));
  float s = v0 + v1 + v2 + v3;
  float q = v0 * v0 + v1 * v1 + v2 * v2 + v3 * v3;
  #pragma unroll
  for (int d = 32; d >= 1; d >>= 1) { s += __shfl_xor(s, d); q += __shfl_xor(q, d); }
  __shared__ float red[8];
  const int lane = t & 63, w = t >> 6;
  if (lane == 0) { red[w] = s; red[4 + w] = q; }
  __syncthreads();
  float S = red[0] + red[1] + red[2] + red[3];
  float Qs = red[4] + red[5] + red[6] + red[7];
  const float mu = S * (1.f / 1024.f);
  const float var = Qs * (1.f / 1024.f) - mu * mu;
  const float rs = rsqrtf(var + 1e-5f);
  float4 gv = *(const float4*)&gamma[d0];
  float4 bv = *(const float4*)&beta[d0];
  float o0 = (v0 - mu) * rs * gv.x + bv.x;
  float o1 = (v1 - mu) * rs * gv.y + bv.y;
  float o2 = (v2 - mu) * rs * gv.z + bv.z;
  float o3 = (v3 - mu) * rs * gv.w + bv.w;
  if (LAST) {
    *(float4*)&fout[base + d0] = make_float4(o0, o1, o2, o3);
  } else {
    uint2 pk;
    pk.x = (uint32_t)f2bf(o0) | ((uint32_t)f2bf(o1) << 16);
    pk.y = (uint32_t)f2bf(o2) | ((uint32_t)f2bf(o3) << 16);
    *(uint2*)&xbf[base + d0] = pk;
  }
}

// ---------------------------------------------------------------------------
// Cross attention v2: per block = 64 q-rows x one (b,h), 4 waves.
// K read direct from global (L2-resident); V read direct from pre-transposed
// vtb[((b*16+h)*64+d)*128 + j] (zero-padded j>=100 by memset).
// P goes through LDS (intra-wave only -> NO barriers).
// ---------------------------------------------------------------------------
__global__ __launch_bounds__(256) void attn_v2(
    const u16* __restrict__ Q, const u16* __restrict__ Kb,
    const u16* __restrict__ Vtb, const int* __restrict__ mask,
    u16* __restrict__ Out)
{
  __shared__ u16 ldsP[64 * 136];

  const int tid = threadIdx.x, lane = tid & 63, w = tid >> 6;
  const int qb = blockIdx.x, bh = blockIdx.y;
  const int b = bh >> 4, h = bh & 15;
  const int fr = lane & 15, g = lane >> 4, fo = g * 8;

  // Q fragments (global, coalesced-ish b128)
  const size_t qrow = (size_t)(b * 2048 + qb * 64 + w * 16 + fr) * 1024 + h * 64;
  bf16x8 qf0 = *(const bf16x8*)&Q[qrow + fo];
  bf16x8 qf1 = *(const bf16x8*)&Q[qrow + 32 + fo];

  // mask adds (predicated register loads, no LDS)
  float madd[7];
  #pragma unroll
  for (int t = 0; t < 7; t++) {
    int col = t * 16 + fr;
    int mv = (col < 100) ? mask[b * 100 + col] : 0;
    madd[t] = mv ? 0.f : -1e30f;
  }

  // QK^T: K fragments direct from global (L2)
  float sc[7][4];
  #pragma unroll
  for (int t = 0; t < 7; t++) {
    int col = t * 16 + fr;
    int jr = (col < 100) ? col : 99;          // clamp address; madd kills value
    const u16* kp = Kb + (size_t)(b * 100 + jr) * 1024 + h * 64;
    bf16x8 kf0 = *(const bf16x8*)&kp[fo];
    bf16x8 kf1 = *(const bf16x8*)&kp[32 + fo];
    f32x4 a = {};
    a = mfma_16x16x32(qf0, kf0, a);
    a = mfma_16x16x32(qf1, kf1, a);
    #pragma unroll
    for (int r = 0; r < 4; r++)
      sc[t][r] = a[r] * 0.125f + madd[t];
  }

  // softmax per row (row = w*16 + g*4 + r; reduce over fr via 16-lane shfl)
  #pragma unroll
  for (int r = 0; r < 4; r++) {
    float m = sc[0][r];
    #pragma unroll
    for (int t = 1; t < 7; t++) m = fmaxf(m, sc[t][r]);
    #pragma unroll
    for (int d = 8; d >= 1; d >>= 1) m = fmaxf(m, __shfl_xor(m, d));
    float ssum = 0.f;
    #pragma unroll
    for (int t = 0; t < 7; t++) { float p = __expf(sc[t][r] - m); sc[t][r] = p; ssum += p; }
    #pragma unroll
    for (int d = 8; d >= 1; d >>= 1) ssum += __shfl_xor(ssum, d);
    float is = 1.f / ssum;
    #pragma unroll
    for (int t = 0; t < 7; t++)
      ldsP[(w * 16 + g * 4 + r) * 136 + t * 16 + fr] = f2bf(sc[t][r] * is);
  }
  // zero tail cols 112..135 of this wave's 16 rows (lane: row=fr, cols g*6)
  {
    u16* zp = &ldsP[(w * 16 + fr) * 136 + 112 + g * 6];
    #pragma unroll
    for (int i = 0; i < 6; i++) zp[i] = 0;
  }
  // intra-wave write->read: compiler inserts lgkmcnt wait; no barrier needed.

  // P @ V : A=P rows (own wave's rows), B=Vt rows direct from global
  bf16x8 pa[4];
  #pragma unroll
  for (int kk = 0; kk < 4; kk++)
    pa[kk] = *(const bf16x8*)&ldsP[(w * 16 + fr) * 136 + kk * 32 + fo];
  const u16* vtbase = Vtb + (size_t)bh * 64 * 128;
  #pragma unroll
  for (int nt = 0; nt < 4; nt++) {
    f32x4 a = {};
    #pragma unroll
    for (int kk = 0; kk < 4; kk++) {
      bf16x8 vf = *(const bf16x8*)&vtbase[(size_t)(nt * 16 + fr) * 128 + kk * 32 + fo];
      a = mfma_16x16x32(pa[kk], vf, a);
    }
    #pragma unroll
    for (int r = 0; r < 4; r++) {
      size_t orow = (size_t)(b * 2048 + qb * 64 + w * 16 + g * 4 + r) * 1024 + h * 64 + nt * 16 + fr;
      Out[orow] = f2bf(a[r]);
    }
  }
}

// ---------------------------------------------------------------------------
extern "C" void kernel_launch(void* const* d_in, const int* in_sizes, int n_in,
                              void* d_out, int out_size, void* d_ws, size_t ws_size,
                              hipStream_t stream) {
  const float* video = (const float*)d_in[0];
  const float* text  = (const float*)d_in[1];
  const int*   text_mask = (const int*)d_in[2];
  const float* Wq_w = (const float*)d_in[3];
  const float* Wq_b = (const float*)d_in[4];
  const float* Wk_w = (const float*)d_in[5];
  const float* Wk_b = (const float*)d_in[6];
  const float* Wv_w = (const float*)d_in[7];
  const float* Wv_b = (const float*)d_in[8];
  const float* Wo_w = (const float*)d_in[9];
  const float* Wo_b = (const float*)d_in[10];
  const float* fc1_w = (const float*)d_in[11];
  const float* fc1_b = (const float*)d_in[12];
  const float* fc2_w = (const float*)d_in[13];
  const float* fc2_b = (const float*)d_in[14];
  const float* n2_g = (const float*)d_in[15];
  const float* n2_b = (const float*)d_in[16];
  const float* n3_g = (const float*)d_in[17];
  const float* n3_b = (const float*)d_in[18];

  char* ws = (char*)d_ws;
  size_t off = 0;
  auto alloc = [&](size_t bytes) {
    char* p = ws + off;
    off += (bytes + 255) & ~(size_t)255;
    return p;
  };
  u16* vbf = (u16*)alloc((size_t)8192 * 1024 * 2);     // 16 MB residual (bf16)
  u16* tbf = (u16*)alloc((size_t)400 * 512 * 2);       // text bf16
  u16* wqT = (u16*)alloc((size_t)1024 * 1024 * 2);
  u16* wkT = (u16*)alloc((size_t)1024 * 512 * 2);
  u16* wvT = (u16*)alloc((size_t)1024 * 512 * 2);
  u16* woT = (u16*)alloc((size_t)1024 * 1024 * 2);
  u16* f1T = (u16*)alloc((size_t)4096 * 1024 * 2);
  u16* f2T = (u16*)alloc((size_t)1024 * 4096 * 2);
  char* S = alloc((size_t)35192832);                   // union scratch
  u16* qbf  = (u16*)S;                                 // 16 MB
  u16* kbf  = (u16*)(S + 16777216);                    // 0.78 MB
  u16* abf  = (u16*)(S + 16777216 + 1638400);          // 16 MB
  u16* h1c  = (u16*)S;                                 // 32 MB (aliases q/k/a)
  u16* vtb  = (u16*)alloc((size_t)64 * 64 * 128 * 2);  // 2 MB V^T (NOT aliased)
  u16* dbf  = (u16*)alloc((size_t)8192 * 1024 * 2);    // 16 MB delta
  float* fout = (float*)d_out;

  // zero vtb pad once per launch (before any V gemm writes)
  hipMemsetAsync(vtb, 0, (size_t)64 * 64 * 128 * 2, stream);

  pe_video_k<<<8192, 256, 0, stream>>>(video, vbf);
  pe_text_k<<<400, 128, 0, stream>>>(text, tbf);

  dim3 tb(32, 8, 1);
  for (int l = 0; l < 4; ++l) {
    wconv_t<<<dim3(32, 32), tb, 0, stream>>>(Wq_w + (size_t)l * 1024 * 1024, wqT, 1024, 1024);
    wconv_t<<<dim3(32, 16), tb, 0, stream>>>(Wk_w + (size_t)l * 512 * 1024, wkT, 512, 1024);
    wconv_t<<<dim3(32, 16), tb, 0, stream>>>(Wv_w + (size_t)l * 512 * 1024, wvT, 512, 1024);
    wconv_t<<<dim3(32, 32), tb, 0, stream>>>(Wo_w + (size_t)l * 1024 * 1024, woT, 1024, 1024);
    wconv_t<<<dim3(128, 32), tb, 0, stream>>>(fc1_w + (size_t)l * 1024 * 4096, f1T, 1024, 4096);
    wconv_t<<<dim3(32, 128), tb, 0, stream>>>(fc2_w + (size_t)l * 4096 * 1024, f2T, 4096, 1024);

    gemm_ring<4, true, false, false><<<dim3(64, 4), 512, 0, stream>>>(
        vbf, 1024, wqT, 1024, Wq_b + l * 1024, qbf, 1024, 8192, 1024, 1024);
    gemm_bt<false><<<dim3(4, 8), 256, 0, stream>>>(
        tbf, 512, wkT, 512, Wk_b + l * 1024, kbf, 1024, 400, 1024, 512);
    gemm_bt<true><<<dim3(4, 8), 256, 0, stream>>>(
        tbf, 512, wvT, 512, Wv_b + l * 1024, vtb, 1024, 400, 1024, 512);
    attn_v2<<<dim3(32, 64), 256, 0, stream>>>(qbf, kbf, vtb, text_mask, abf);
    gemm_ring<4, true, false, false><<<dim3(64, 4), 512, 0, stream>>>(
        abf, 1024, woT, 1024, Wo_b + l * 1024, dbf, 1024, 8192, 1024, 1024);
    ln2<false><<<8192, 256, 0, stream>>>(vbf, dbf, n2_g + l * 1024, n2_b + l * 1024, vbf, nullptr);

    for (int c = 0; c < 2; ++c) {
      gemm_ring<8, true, true, false><<<dim3(32, 8), 512, 0, stream>>>(
          vbf, 1024, f1T + (size_t)c * 2048 * 1024, 1024,
          fc1_b + l * 4096 + c * 2048, h1c, 2048, 8192, 2048, 1024);
      if (c == 0)
        gemm_ring<4, true, false, false><<<dim3(64, 4), 512, 0, stream>>>(
            h1c, 2048, f2T + (size_t)c * 2048, 4096,
            fc2_b + l * 1024, dbf, 1024, 8192, 1024, 2048);
      else
        gemm_ring<4, true, false, true><<<dim3(64, 4), 512, 0, stream>>>(
            h1c, 2048, f2T + (size_t)c * 2048, 4096,
            nullptr, dbf, 1024, 8192, 1024, 2048);
    }
    if (l == 3)
      ln2<true><<<8192, 256, 0, stream>>>(vbf, dbf, n3_g + l * 1024, n3_b + l * 1024, nullptr, fout);
    else
      ln2<false><<<8192, 256, 0, stream>>>(vbf, dbf, n3_g + l * 1024, n3_b + l * 1024, vbf, nullptr);
  }
}

// Round 5
// 1314.151 us; speedup vs baseline: 1.2934x; 1.0612x over previous
//
#include <hip/hip_runtime.h>
#include <cstdint>
#include <cstddef>

typedef unsigned short u16;
typedef __attribute__((ext_vector_type(8))) __bf16 bf16x8;
typedef __attribute__((ext_vector_type(4))) float f32x4;

__device__ __forceinline__ f32x4 mfma_16x16x32(bf16x8 a, bf16x8 b, f32x4 c) {
  return __builtin_amdgcn_mfma_f32_16x16x32_bf16(a, b, c, 0, 0, 0);
}

__device__ __forceinline__ u16 f2bf(float f) {
  union { float f; uint32_t u; } c; c.f = f;
  uint32_t u = c.u + 0x7FFFu + ((c.u >> 16) & 1u);
  return (u16)(u >> 16);
}

__device__ __forceinline__ float bf2f(u16 x) {
  union { uint32_t u; float f; } c; c.u = ((uint32_t)x) << 16;
  return c.f;
}

__device__ __forceinline__ void gload_lds16(const void* g, void* l) {
  __builtin_amdgcn_global_load_lds(
      (__attribute__((address_space(1))) void*)(uintptr_t)g,
      (__attribute__((address_space(3))) void*)l, 16, 0, 0);
}

// ===========================================================================
// Deep-pipelined ring GEMM v2.  C[M,N] = A[M,K] @ Bt[N,K]^T (+bias)(+C)(ReLU)
// MR=8: BM=256, MR=4: BM=128.  BN=256. 512 threads = 8 waves (2x4).
// BK=32/step; 4-slot LDS ring; prefetch dist 3; counted vmcnt; ONE barrier
// per K-step (WAR closed by lgkmcnt(0) before it, RAW by counted vmcnt).
// Swizzle sigma(r)=(r>>1)&3 on 16B slots: consecutive 8 lanes hit 8 distinct
// bank granules (derivation in journal). Applied to BOTH the pre-swizzled
// global source of global_load_lds and the ds_read offset.
// ===========================================================================
template<int MR, bool OUT_BF16, bool RELU, bool ACC>
__global__ __launch_bounds__(512, 2) void gemm_ring(
    const u16* __restrict__ A, int lda, const u16* __restrict__ Bt, int ldb,
    const float* __restrict__ bias, void* Cout, int ldc,
    int M, int N, int K)
{
  constexpr int BM = MR * 32;
  constexpr int SLOT = (BM + 256) * 32;
  __shared__ u16 ring[4 * SLOT];

  const int tid = threadIdx.x;
  const int lane = tid & 63, wave = tid >> 6;
  const int wm = wave >> 2, wn = wave & 3;
  const int m0 = blockIdx.x * BM, n0 = blockIdx.y * 256;

  // staging: chunk c -> row r=c>>2, physical slot q=c&3 holds logical slot
  // q ^ ((r>>1)&3); fetch that logical slot from global.
  const int cA0 = tid, rA0 = cA0 >> 2;
  const u16* gA0 = A + (size_t)(m0 + rA0) * lda + (((cA0 & 3) ^ ((rA0 >> 1) & 3)) * 8);
  const int cA1 = tid + 512, rA1 = cA1 >> 2;
  const u16* gA1 = A + (size_t)(m0 + (MR == 8 ? rA1 : 0)) * lda + (((cA1 & 3) ^ ((rA1 >> 1) & 3)) * 8);
  const int cB0 = tid, rB0 = cB0 >> 2;
  const int cB1 = tid + 512, rB1 = cB1 >> 2;
  const u16* gB0 = Bt + (size_t)(n0 + rB0) * ldb + (((cB0 & 3) ^ ((rB0 >> 1) & 3)) * 8);
  const u16* gB1 = Bt + (size_t)(n0 + rB1) * ldb + (((cB1 & 3) ^ ((rB1 >> 1) & 3)) * 8);

  const int NK = K >> 5;

  auto STAGE = [&](int s) {
    u16* Sb = &ring[(s & 3) * SLOT];
    const int ko = s * 32;
    gload_lds16(gA0 + ko, Sb + cA0 * 8);
    if constexpr (MR == 8) gload_lds16(gA1 + ko, Sb + cA1 * 8);
    gload_lds16(gB0 + ko, Sb + BM * 32 + cB0 * 8);
    gload_lds16(gB1 + ko, Sb + BM * 32 + cB1 * 8);
  };
  // LPT = 4 (MR=8) or 3 (MR=4); keep <= ahead*LPT outstanding
  auto WAITV = [&](int ahead) {
    if (ahead >= 2) {
      if constexpr (MR == 8) asm volatile("s_waitcnt vmcnt(8)" ::: "memory");
      else                   asm volatile("s_waitcnt vmcnt(6)" ::: "memory");
    } else if (ahead == 1) {
      if constexpr (MR == 8) asm volatile("s_waitcnt vmcnt(4)" ::: "memory");
      else                   asm volatile("s_waitcnt vmcnt(3)" ::: "memory");
    } else {
      asm volatile("s_waitcnt vmcnt(0)" ::: "memory");
    }
  };

  // ds_read lane constants: logical slot g lives at physical g ^ ((fr>>1)&3)
  const int fr = lane & 15, g = lane >> 4;
  const int foff = fr * 32 + ((g ^ ((fr >> 1) & 3)) * 8);

  f32x4 acc[MR][4];
  #pragma unroll
  for (int m = 0; m < MR; m++)
    #pragma unroll
    for (int n = 0; n < 4; n++) acc[m][n] = f32x4{0.f, 0.f, 0.f, 0.f};

  for (int i = 0; i < 3 && i < NK; ++i) STAGE(i);
  WAITV(NK - 1 < 2 ? NK - 1 : 2);
  __builtin_amdgcn_s_barrier();
  __builtin_amdgcn_sched_barrier(0);

  for (int s = 0; s < NK; ++s) {
    const u16* As = &ring[(s & 3) * SLOT];
    const u16* Bs = As + BM * 32;

    bf16x8 bf[4];
    #pragma unroll
    for (int n = 0; n < 4; n++)
      bf[n] = *(const bf16x8*)(Bs + (wn * 64 + n * 16) * 32 + foff);
    bf16x8 af[4];
    #pragma unroll
    for (int m = 0; m < 4; m++)
      af[m] = *(const bf16x8*)(As + (wm * (MR * 16) + m * 16) * 32 + foff);

    if (s + 3 < NK) STAGE(s + 3);

    __builtin_amdgcn_s_setprio(1);
    #pragma unroll
    for (int m = 0; m < 4; m++)
      #pragma unroll
      for (int n = 0; n < 4; n++)
        acc[m][n] = mfma_16x16x32(af[m], bf[n], acc[m][n]);
    __builtin_amdgcn_s_setprio(0);

    if constexpr (MR == 8) {
      bf16x8 af2[4];
      #pragma unroll
      for (int m = 0; m < 4; m++)
        af2[m] = *(const bf16x8*)(As + (wm * 128 + (m + 4) * 16) * 32 + foff);
      __builtin_amdgcn_s_setprio(1);
      #pragma unroll
      for (int m = 0; m < 4; m++)
        #pragma unroll
        for (int n = 0; n < 4; n++)
          acc[m + 4][n] = mfma_16x16x32(af2[m], bf[n], acc[m + 4][n]);
      __builtin_amdgcn_s_setprio(0);
    }

    // RAW: next step's slot fully staged (counted, never drains in steady state)
    {
      int im = (s + 3 < NK - 1) ? s + 3 : NK - 1;
      WAITV(im - (s + 1));
    }
    // WAR: this wave's ds_reads of slot s physically complete before anyone
    // stages into slot (s+4)&3 == s&3 after the barrier.
    asm volatile("s_waitcnt lgkmcnt(0)" ::: "memory");
    __builtin_amdgcn_sched_barrier(0);
    __builtin_amdgcn_s_barrier();
    __builtin_amdgcn_sched_barrier(0);
  }

  #pragma unroll
  for (int n = 0; n < 4; n++) {
    const int gcol = n0 + wn * 64 + n * 16 + fr;
    const float bv = bias ? bias[gcol] : 0.f;
    #pragma unroll
    for (int m = 0; m < MR; m++) {
      #pragma unroll
      for (int r = 0; r < 4; r++) {
        const int grow = m0 + wm * (MR * 16) + m * 16 + g * 4 + r;
        float v = acc[m][n][r] + bv;
        if (ACC) v += bf2f(((const u16*)Cout)[(size_t)grow * ldc + gcol]);
        if (RELU) v = fmaxf(v, 0.f);
        if (OUT_BF16) ((u16*)Cout)[(size_t)grow * ldc + gcol] = f2bf(v);
        else         ((float*)Cout)[(size_t)grow * ldc + gcol] = v;
      }
    }
  }
}

// ---------------------------------------------------------------------------
// Small GEMM (M=400 K/V projections): 128x128 tile, BK=32.
// TRANS=true: store C transposed into vtb[((b*16+h)*64+d)*128 + j]
// ---------------------------------------------------------------------------
template<bool TRANS>
__global__ __launch_bounds__(256, 2) void gemm_bt(
    const u16* __restrict__ A, int lda, const u16* __restrict__ Bt, int ldb,
    const float* __restrict__ bias, u16* Cout, int ldc,
    int M, int N, int K)
{
  __shared__ u16 ldsA[128 * 32];
  __shared__ u16 ldsB[128 * 32];

  const int tid = threadIdx.x;
  const int lane = tid & 63, wave = tid >> 6;
  const int wr = wave >> 1, wc = wave & 1;
  const int m0 = blockIdx.x * 128, n0 = blockIdx.y * 128;

  const int c0 = tid, c1 = tid + 256;
  const int ar0 = c0 >> 2, ak0 = (c0 & 3) * 8;
  const int ar1 = c1 >> 2, ak1 = (c1 & 3) * 8;

  const bool av0 = (m0 + ar0) < M;
  const bool av1 = (m0 + ar1) < M;
  const u16* Ag0 = A + (size_t)(m0 + ar0) * lda + ak0;
  const u16* Ag1 = A + (size_t)(m0 + ar1) * lda + ak1;
  const u16* Bg0 = Bt + (size_t)(n0 + ar0) * ldb + ak0;
  const u16* Bg1 = Bt + (size_t)(n0 + ar1) * ldb + ak1;

  f32x4 acc[4][4] = {};
  const int fr = lane & 15, fo = (lane >> 4) * 8;

  for (int k0 = 0; k0 < K; k0 += 32) {
    if (av0) gload_lds16(Ag0 + k0, &ldsA[c0 * 8]);
    if (av1) gload_lds16(Ag1 + k0, &ldsA[c1 * 8]);
    gload_lds16(Bg0 + k0, &ldsB[c0 * 8]);
    gload_lds16(Bg1 + k0, &ldsB[c1 * 8]);
    asm volatile("s_waitcnt vmcnt(0)" ::: "memory");
    __syncthreads();

    bf16x8 af[4], bfr[4];
    #pragma unroll
    for (int m = 0; m < 4; m++)
      af[m] = *(const bf16x8*)&ldsA[(wr * 64 + m * 16 + fr) * 32 + fo];
    #pragma unroll
    for (int n = 0; n < 4; n++)
      bfr[n] = *(const bf16x8*)&ldsB[(wc * 64 + n * 16 + fr) * 32 + fo];
    #pragma unroll
    for (int m = 0; m < 4; m++)
      #pragma unroll
      for (int n = 0; n < 4; n++)
        acc[m][n] = mfma_16x16x32(af[m], bfr[n], acc[m][n]);
    __syncthreads();
  }

  const int g = lane >> 4;
  #pragma unroll
  for (int m = 0; m < 4; m++) {
    #pragma unroll
    for (int n = 0; n < 4; n++) {
      const int gcol = n0 + wc * 64 + n * 16 + fr;
      const float bv = bias[gcol];
      #pragma unroll
      for (int r = 0; r < 4; r++) {
        const int grow = m0 + wr * 64 + m * 16 + g * 4 + r;
        if (grow < M) {
          float v = acc[m][n][r] + bv;
          if (TRANS) {
            int bb = grow / 100, jj = grow - bb * 100;
            int h = gcol >> 6, d = gcol & 63;
            Cout[(size_t)(((bb * 16 + h) * 64 + d)) * 128 + jj] = f2bf(v);
          } else {
            Cout[(size_t)grow * ldc + gcol] = f2bf(v);
          }
        }
      }
    }
  }
}

// ---------------------------------------------------------------------------
// Weight transpose+convert: src f32 [K][N] -> dst bf16 [N][K]
// ---------------------------------------------------------------------------
__global__ void wconv_t(const float* __restrict__ src, u16* __restrict__ dst,
                        int K, int N)
{
  __shared__ float tile[32][33];
  const int n0 = blockIdx.x * 32, k0 = blockIdx.y * 32;
  const int tx = threadIdx.x, ty = threadIdx.y;
  #pragma unroll
  for (int i = 0; i < 4; i++)
    tile[ty + i * 8][tx] = src[(size_t)(k0 + ty + i * 8) * N + n0 + tx];
  __syncthreads();
  #pragma unroll
  for (int i = 0; i < 4; i++)
    dst[(size_t)(n0 + ty + i * 8) * K + k0 + tx] = f2bf(tile[tx][ty + i * 8]);
}

// ---------------------------------------------------------------------------
// Positional encoding add -> bf16 only
// ---------------------------------------------------------------------------
__global__ __launch_bounds__(256) void pe_video_k(const float* __restrict__ video,
                                                  u16* __restrict__ vbf)
{
  const int r = blockIdx.x;
  const int s = r & 2047;
  const int d0 = threadIdx.x * 4;
  const size_t base = (size_t)r * 1024 + d0;
  float4 v = *(const float4*)&video[base];
  const float coef = -9.210340371976184f / 1024.f;
  float o[4];
  float in[4] = {v.x, v.y, v.z, v.w};
  #pragma unroll
  for (int i = 0; i < 4; i++) {
    int d = d0 + i;
    int j = d >> 1;
    float dv = expf((float)(2 * j) * coef);
    float arg = (float)s * dv;
    float pe = (d & 1) ? cosf(arg) : sinf(arg);
    o[i] = in[i] + pe;
  }
  uint2 pk;
  pk.x = (uint32_t)f2bf(o[0]) | ((uint32_t)f2bf(o[1]) << 16);
  pk.y = (uint32_t)f2bf(o[2]) | ((uint32_t)f2bf(o[3]) << 16);
  *(uint2*)&vbf[base] = pk;
}

__global__ __launch_bounds__(128) void pe_text_k(const float* __restrict__ text,
                                                 u16* __restrict__ tbf)
{
  const int r = blockIdx.x;
  const int s = r % 100;
  const int d0 = threadIdx.x * 4;
  const size_t base = (size_t)r * 512 + d0;
  float4 v = *(const float4*)&text[base];
  const float coef = -9.210340371976184f / 512.f;
  float o[4];
  float in[4] = {v.x, v.y, v.z, v.w};
  #pragma unroll
  for (int i = 0; i < 4; i++) {
    int d = d0 + i;
    int j = d >> 1;
    float dv = expf((float)(2 * j) * coef);
    float arg = (float)s * dv;
    float pe = (d & 1) ? cosf(arg) : sinf(arg);
    o[i] = in[i] + pe;
  }
  uint2 pk;
  pk.x = (uint32_t)f2bf(o[0]) | ((uint32_t)f2bf(o[1]) << 16);
  pk.y = (uint32_t)f2bf(o[2]) | ((uint32_t)f2bf(o[3]) << 16);
  *(uint2*)&tbf[base] = pk;
}

// ---------------------------------------------------------------------------
// LayerNorm, bf16 residual stream: x' = LN(x + delta)*g+b
// ---------------------------------------------------------------------------
template<bool LAST>
__global__ __launch_bounds__(256) void ln2(const u16* __restrict__ xin,
                                           const u16* __restrict__ delta,
                                           const float* __restrict__ gamma,
                                           const float* __restrict__ beta,
                                           u16* __restrict__ xbf,
                                           float* __restrict__ fout)
{
  const int row = blockIdx.x;
  const size_t base = (size_t)row * 1024;
  const int t = threadIdx.x;
  const int d0 = t * 4;
  uint2 xv = *(const uint2*)&xin[base + d0];
  uint2 dv = *(const uint2*)&delta[base + d0];
  float v0 = bf2f((u16)(xv.x & 0xFFFF)) + bf2f((u16)(dv.x & 0xFFFF));
  float v1 = bf2f((u16)(xv.x >> 16))    + bf2f((u16)(dv.x >> 16));
  float v2 = bf2f((u16)(xv.y & 0xFFFF)) + bf2f((u16)(dv.y & 0xFFFF));
  float v3 = bf2f((u16)(xv.y >> 16))    + bf2f((u16)(dv.y >> 16));
  float s = v0 + v1 + v2 + v3;
  float q = v0 * v0 + v1 * v1 + v2 * v2 + v3 * v3;
  #pragma unroll
  for (int d = 32; d >= 1; d >>= 1) { s += __shfl_xor(s, d); q += __shfl_xor(q, d); }
  __shared__ float red[8];
  const int lane = t & 63, w = t >> 6;
  if (lane == 0) { red[w] = s; red[4 + w] = q; }
  __syncthreads();
  float S = red[0] + red[1] + red[2] + red[3];
  float Qs = red[4] + red[5] + red[6] + red[7];
  const float mu = S * (1.f / 1024.f);
  const float var = Qs * (1.f / 1024.f) - mu * mu;
  const float rs = rsqrtf(var + 1e-5f);
  float4 gv = *(const float4*)&gamma[d0];
  float4 bv = *(const float4*)&beta[d0];
  float o0 = (v0 - mu) * rs * gv.x + bv.x;
  float o1 = (v1 - mu) * rs * gv.y + bv.y;
  float o2 = (v2 - mu) * rs * gv.z + bv.z;
  float o3 = (v3 - mu) * rs * gv.w + bv.w;
  if (LAST) {
    *(float4*)&fout[base + d0] = make_float4(o0, o1, o2, o3);
  } else {
    uint2 pk;
    pk.x = (uint32_t)f2bf(o0) | ((uint32_t)f2bf(o1) << 16);
    pk.y = (uint32_t)f2bf(o2) | ((uint32_t)f2bf(o3) << 16);
    *(uint2*)&xbf[base + d0] = pk;
  }
}

// ---------------------------------------------------------------------------
// Cross attention v2 (passed round 3): K from global (L2), V pre-transposed,
// P via LDS intra-wave, zero barriers.
// ---------------------------------------------------------------------------
__global__ __launch_bounds__(256) void attn_v2(
    const u16* __restrict__ Q, const u16* __restrict__ Kb,
    const u16* __restrict__ Vtb, const int* __restrict__ mask,
    u16* __restrict__ Out)
{
  __shared__ u16 ldsP[64 * 136];

  const int tid = threadIdx.x, lane = tid & 63, w = tid >> 6;
  const int qb = blockIdx.x, bh = blockIdx.y;
  const int b = bh >> 4, h = bh & 15;
  const int fr = lane & 15, g = lane >> 4, fo = g * 8;

  const size_t qrow = (size_t)(b * 2048 + qb * 64 + w * 16 + fr) * 1024 + h * 64;
  bf16x8 qf0 = *(const bf16x8*)&Q[qrow + fo];
  bf16x8 qf1 = *(const bf16x8*)&Q[qrow + 32 + fo];

  float madd[7];
  #pragma unroll
  for (int t = 0; t < 7; t++) {
    int col = t * 16 + fr;
    int mv = (col < 100) ? mask[b * 100 + col] : 0;
    madd[t] = mv ? 0.f : -1e30f;
  }

  float sc[7][4];
  #pragma unroll
  for (int t = 0; t < 7; t++) {
    int col = t * 16 + fr;
    int jr = (col < 100) ? col : 99;
    const u16* kp = Kb + (size_t)(b * 100 + jr) * 1024 + h * 64;
    bf16x8 kf0 = *(const bf16x8*)&kp[fo];
    bf16x8 kf1 = *(const bf16x8*)&kp[32 + fo];
    f32x4 a = {};
    a = mfma_16x16x32(qf0, kf0, a);
    a = mfma_16x16x32(qf1, kf1, a);
    #pragma unroll
    for (int r = 0; r < 4; r++)
      sc[t][r] = a[r] * 0.125f + madd[t];
  }

  #pragma unroll
  for (int r = 0; r < 4; r++) {
    float m = sc[0][r];
    #pragma unroll
    for (int t = 1; t < 7; t++) m = fmaxf(m, sc[t][r]);
    #pragma unroll
    for (int d = 8; d >= 1; d >>= 1) m = fmaxf(m, __shfl_xor(m, d));
    float ssum = 0.f;
    #pragma unroll
    for (int t = 0; t < 7; t++) { float p = __expf(sc[t][r] - m); sc[t][r] = p; ssum += p; }
    #pragma unroll
    for (int d = 8; d >= 1; d >>= 1) ssum += __shfl_xor(ssum, d);
    float is = 1.f / ssum;
    #pragma unroll
    for (int t = 0; t < 7; t++)
      ldsP[(w * 16 + g * 4 + r) * 136 + t * 16 + fr] = f2bf(sc[t][r] * is);
  }
  {
    u16* zp = &ldsP[(w * 16 + fr) * 136 + 112 + g * 6];
    #pragma unroll
    for (int i = 0; i < 6; i++) zp[i] = 0;
  }

  bf16x8 pa[4];
  #pragma unroll
  for (int kk = 0; kk < 4; kk++)
    pa[kk] = *(const bf16x8*)&ldsP[(w * 16 + fr) * 136 + kk * 32 + fo];
  const u16* vtbase = Vtb + (size_t)bh * 64 * 128;
  #pragma unroll
  for (int nt = 0; nt < 4; nt++) {
    f32x4 a = {};
    #pragma unroll
    for (int kk = 0; kk < 4; kk++) {
      bf16x8 vf = *(const bf16x8*)&vtbase[(size_t)(nt * 16 + fr) * 128 + kk * 32 + fo];
      a = mfma_16x16x32(pa[kk], vf, a);
    }
    #pragma unroll
    for (int r = 0; r < 4; r++) {
      size_t orow = (size_t)(b * 2048 + qb * 64 + w * 16 + g * 4 + r) * 1024 + h * 64 + nt * 16 + fr;
      Out[orow] = f2bf(a[r]);
    }
  }
}

// ---------------------------------------------------------------------------
extern "C" void kernel_launch(void* const* d_in, const int* in_sizes, int n_in,
                              void* d_out, int out_size, void* d_ws, size_t ws_size,
                              hipStream_t stream) {
  const float* video = (const float*)d_in[0];
  const float* text  = (const float*)d_in[1];
  const int*   text_mask = (const int*)d_in[2];
  const float* Wq_w = (const float*)d_in[3];
  const float* Wq_b = (const float*)d_in[4];
  const float* Wk_w = (const float*)d_in[5];
  const float* Wk_b = (const float*)d_in[6];
  const float* Wv_w = (const float*)d_in[7];
  const float* Wv_b = (const float*)d_in[8];
  const float* Wo_w = (const float*)d_in[9];
  const float* Wo_b = (const float*)d_in[10];
  const float* fc1_w = (const float*)d_in[11];
  const float* fc1_b = (const float*)d_in[12];
  const float* fc2_w = (const float*)d_in[13];
  const float* fc2_b = (const float*)d_in[14];
  const float* n2_g = (const float*)d_in[15];
  const float* n2_b = (const float*)d_in[16];
  const float* n3_g = (const float*)d_in[17];
  const float* n3_b = (const float*)d_in[18];

  char* ws = (char*)d_ws;
  size_t off = 0;
  auto alloc = [&](size_t bytes) {
    char* p = ws + off;
    off += (bytes + 255) & ~(size_t)255;
    return p;
  };
  u16* vbf = (u16*)alloc((size_t)8192 * 1024 * 2);     // 16 MB residual (bf16)
  u16* tbf = (u16*)alloc((size_t)400 * 512 * 2);
  u16* wqT = (u16*)alloc((size_t)1024 * 1024 * 2);
  u16* wkT = (u16*)alloc((size_t)1024 * 512 * 2);
  u16* wvT = (u16*)alloc((size_t)1024 * 512 * 2);
  u16* woT = (u16*)alloc((size_t)1024 * 1024 * 2);
  u16* f1T = (u16*)alloc((size_t)4096 * 1024 * 2);
  u16* f2T = (u16*)alloc((size_t)1024 * 4096 * 2);
  char* S = alloc((size_t)35192832);                   // union scratch
  u16* qbf  = (u16*)S;
  u16* kbf  = (u16*)(S + 16777216);
  u16* abf  = (u16*)(S + 16777216 + 1638400);
  u16* h1c  = (u16*)S;
  u16* vtb  = (u16*)alloc((size_t)64 * 64 * 128 * 2);  // 2 MB V^T (not aliased)
  u16* dbf  = (u16*)alloc((size_t)8192 * 1024 * 2);
  float* fout = (float*)d_out;

  hipMemsetAsync(vtb, 0, (size_t)64 * 64 * 128 * 2, stream);

  pe_video_k<<<8192, 256, 0, stream>>>(video, vbf);
  pe_text_k<<<400, 128, 0, stream>>>(text, tbf);

  dim3 tb(32, 8, 1);
  for (int l = 0; l < 4; ++l) {
    wconv_t<<<dim3(32, 32), tb, 0, stream>>>(Wq_w + (size_t)l * 1024 * 1024, wqT, 1024, 1024);
    wconv_t<<<dim3(32, 16), tb, 0, stream>>>(Wk_w + (size_t)l * 512 * 1024, wkT, 512, 1024);
    wconv_t<<<dim3(32, 16), tb, 0, stream>>>(Wv_w + (size_t)l * 512 * 1024, wvT, 512, 1024);
    wconv_t<<<dim3(32, 32), tb, 0, stream>>>(Wo_w + (size_t)l * 1024 * 1024, woT, 1024, 1024);
    wconv_t<<<dim3(128, 32), tb, 0, stream>>>(fc1_w + (size_t)l * 1024 * 4096, f1T, 1024, 4096);
    wconv_t<<<dim3(32, 128), tb, 0, stream>>>(fc2_w + (size_t)l * 4096 * 1024, f2T, 4096, 1024);

    gemm_ring<4, true, false, false><<<dim3(64, 4), 512, 0, stream>>>(
        vbf, 1024, wqT, 1024, Wq_b + l * 1024, qbf, 1024, 8192, 1024, 1024);
    gemm_bt<false><<<dim3(4, 8), 256, 0, stream>>>(
        tbf, 512, wkT, 512, Wk_b + l * 1024, kbf, 1024, 400, 1024, 512);
    gemm_bt<true><<<dim3(4, 8), 256, 0, stream>>>(
        tbf, 512, wvT, 512, Wv_b + l * 1024, vtb, 1024, 400, 1024, 512);
    attn_v2<<<dim3(32, 64), 256, 0, stream>>>(qbf, kbf, vtb, text_mask, abf);
    gemm_ring<4, true, false, false><<<dim3(64, 4), 512, 0, stream>>>(
        abf, 1024, woT, 1024, Wo_b + l * 1024, dbf, 1024, 8192, 1024, 1024);
    ln2<false><<<8192, 256, 0, stream>>>(vbf, dbf, n2_g + l * 1024, n2_b + l * 1024, vbf, nullptr);

    for (int c = 0; c < 2; ++c) {
      gemm_ring<8, true, true, false><<<dim3(32, 8), 512, 0, stream>>>(
          vbf, 1024, f1T + (size_t)c * 2048 * 1024, 1024,
          fc1_b + l * 4096 + c * 2048, h1c, 2048, 8192, 2048, 1024);
      if (c == 0)
        gemm_ring<4, true, false, false><<<dim3(64, 4), 512, 0, stream>>>(
            h1c, 2048, f2T + (size_t)c * 2048, 4096,
            fc2_b + l * 1024, dbf, 1024, 8192, 1024, 2048);
      else
        gemm_ring<4, true, false, true><<<dim3(64, 4), 512, 0, stream>>>(
            h1c, 2048, f2T + (size_t)c * 2048, 4096,
            nullptr, dbf, 1024, 8192, 1024, 2048);
    }
    if (l == 3)
      ln2<true><<<8192, 256, 0, stream>>>(vbf, dbf, n3_g + l * 1024, n3_b + l * 1024, nullptr, fout);
    else
      ln2<false><<<8192, 256, 0, stream>>>(vbf, dbf, n3_g + l * 1024, n3_b + l * 1024, vbf, nullptr);
  }
}